// Round 1
// baseline (7481.197 us; speedup 1.0000x reference)
//
#include <hip/hip_runtime.h>
#include <math.h>

#define TPB 256

__device__ __forceinline__ float wave_sum64(float v) {
#pragma unroll
  for (int o = 32; o > 0; o >>= 1) v += __shfl_down(v, o, 64);
  return v;
}

// ===== 8x8 max pool: [B,1,384,384] -> [B,2304] =====
__global__ __launch_bounds__(TPB) void pool8_kernel(const float* __restrict__ in,
                                                    float* __restrict__ out, int total) {
  int idx = blockIdx.x * TPB + threadIdx.x;
  if (idx >= total) return;
  int b = idx / 2304, yx = idx - b * 2304;
  int y = yx / 48, x = yx - y * 48;
  const float* p = in + ((size_t)b * 384 + (size_t)y * 8) * 384 + (size_t)x * 8;
  float m = -INFINITY;
#pragma unroll
  for (int i = 0; i < 8; ++i) {
#pragma unroll
    for (int j = 0; j < 8; ++j) m = fmaxf(m, p[(size_t)i * 384 + j]);
  }
  out[idx] = m;
}

// ===== bitonic ascending sort of N (power of 2) floats in LDS, 256 threads =====
template <int N>
__device__ void bitonic_sort_asc(float* s) {
  for (int k = 2; k <= N; k <<= 1) {
    for (int j = k >> 1; j > 0; j >>= 1) {
      __syncthreads();
      for (int t = threadIdx.x; t < N; t += TPB) {
        int ixj = t ^ j;
        if (ixj > t) {
          float a = s[t], b = s[ixj];
          bool up = ((t & k) == 0);
          bool sw = up ? (a > b) : (a < b);
          if (sw) { s[t] = b; s[ixj] = a; }
        }
      }
    }
  }
  __syncthreads();
}

// ===== global top-k: per pixel, topk256 over 2304 channels of kg1*gm and kg1*(1-gm) =====
__global__ __launch_bounds__(TPB) void topk_global_kernel(const float* __restrict__ kg1,
                                                          const float* __restrict__ gm,
                                                          float* __restrict__ xcat) {
  __shared__ float sf[4096];
  __shared__ float sb[4096];
  int bid = blockIdx.x;               // b*2304 + yx
  int b = bid / 2304, yx = bid - b * 2304;
  const float* kp = kg1 + (size_t)b * 2304 * 2304 + yx;
  const float* gp = gm + (size_t)b * 2304;
  for (int i = threadIdx.x; i < 4096; i += TPB) {
    float vf = -INFINITY, vb = -INFINITY;
    if (i < 2304) {
      float v = kp[(size_t)i * 2304];
      float g = gp[i];
      vf = v * g;
      vb = v * (1.0f - g);
    }
    sf[i] = vf;
    sb[i] = vb;
  }
  bitonic_sort_asc<4096>(sf);
  xcat[((size_t)b * 1281 + 256 + threadIdx.x) * 2304 + yx] = sf[4095 - threadIdx.x];
  bitonic_sort_asc<4096>(sb);
  xcat[((size_t)b * 1281 + 512 + threadIdx.x) * 2304 + yx] = sb[4095 - threadIdx.x];
}

// ===== local top-k: per pixel, topk256 over 289 window channels of klp*patch etc =====
__global__ __launch_bounds__(TPB) void topk_local_kernel(const float* __restrict__ klp,
                                                         const float* __restrict__ lm,
                                                         float* __restrict__ xcat) {
  __shared__ float sf[512];
  __shared__ float sb[512];
  int bid = blockIdx.x;
  int b = bid / 2304, yx = bid - b * 2304;
  int y = yx / 48, x = yx - y * 48;
  for (int i = threadIdx.x; i < 512; i += TPB) {
    float vf = -INFINITY, vb = -INFINITY;
    if (i < 289) {
      int dy = i / 17, dx = i - dy * 17;
      int sy = y + dy - 8, sx = x + dx - 8;
      float pv = 0.f;
      if (sy >= 0 && sy < 48 && sx >= 0 && sx < 48) pv = lm[(size_t)b * 2304 + sy * 48 + sx];
      float v = klp[((size_t)b * 289 + i) * 2304 + yx];
      vf = v * pv;
      vb = v * (1.0f - pv);
    }
    sf[i] = vf;
    sb[i] = vb;
  }
  bitonic_sort_asc<512>(sf);
  xcat[((size_t)b * 1281 + 768 + threadIdx.x) * 2304 + yx] = sf[511 - threadIdx.x];
  bitonic_sort_asc<512>(sb);
  xcat[((size_t)b * 1281 + 1024 + threadIdx.x) * 2304 + yx] = sb[511 - threadIdx.x];
}

// ===== copy p3 into xcat channels [0,256) =====
__global__ __launch_bounds__(TPB) void copy_p3_kernel(const float* __restrict__ p3,
                                                      float* __restrict__ xcat) {
  int idx = blockIdx.x * TPB + threadIdx.x;
  const int per_b = 256 * 2304;
  if (idx >= 2 * per_b) return;
  int b = idx / per_b, r = idx - b * per_b;
  xcat[(size_t)b * 1281 * 2304 + r] = p3[idx];
}

// ===== copy pm (=lm) into xcat channel 1280 =====
__global__ __launch_bounds__(TPB) void copy_pm_kernel(const float* __restrict__ lm,
                                                      float* __restrict__ xcat) {
  int idx = blockIdx.x * TPB + threadIdx.x;
  if (idx >= 2 * 2304) return;
  int b = idx / 2304, yx = idx - b * 2304;
  xcat[((size_t)b * 1281 + 1280) * 2304 + yx] = lm[idx];
}

// ===== direct 3x3 conv, pad 1. Tile: 16 rows x 48 cols (thread = 3 px in x). =====
// ACT: 0 = bias only, 2 = bias + sigmoid
template <int CO, int ACT>
__global__ __launch_bounds__(TPB) void conv3x3_kernel(
    const float* __restrict__ in, const float* __restrict__ w,
    const float* __restrict__ bias, float* __restrict__ out,
    int Cin, int Cout, int H, int W) {
  const int CIC = 4;
  __shared__ float sin_t[CIC][18 * 50];
  int tid = threadIdx.x;
  int tx = tid & 15, ty = tid >> 4;
  int tilesX = W / 48;
  int bx = blockIdx.x % tilesX, by = blockIdx.x / tilesX;
  int co0 = blockIdx.y * CO;
  int b = blockIdx.z;
  int oy = by * 16 + ty;
  int ox = bx * 48 + tx * 3;
  float acc[CO][3];
#pragma unroll
  for (int c = 0; c < CO; ++c) { acc[c][0] = acc[c][1] = acc[c][2] = 0.f; }
  int gy0 = by * 16 - 1, gx0 = bx * 48 - 1;
  const size_t in_b = (size_t)b * Cin * H * W;
  for (int ci0 = 0; ci0 < Cin; ci0 += CIC) {
    __syncthreads();
    for (int idx = tid; idx < CIC * 900; idx += TPB) {
      int ci = idx / 900, r = idx - ci * 900;
      int row = r / 50, col = r - row * 50;
      int gy = gy0 + row, gx = gx0 + col;
      int cig = ci0 + ci;
      float v = 0.f;
      if (cig < Cin && gy >= 0 && gy < H && gx >= 0 && gx < W)
        v = in[in_b + ((size_t)cig * H + gy) * W + gx];
      sin_t[ci][r] = v;
    }
    __syncthreads();
#pragma unroll
    for (int ci = 0; ci < CIC; ++ci) {
      int cig = ci0 + ci;
      if (cig < Cin) {
        float rin[3][5];
        const float* sp = &sin_t[ci][ty * 50 + tx * 3];
#pragma unroll
        for (int d = 0; d < 5; ++d) {
          rin[0][d] = sp[d];
          rin[1][d] = sp[50 + d];
          rin[2][d] = sp[100 + d];
        }
#pragma unroll
        for (int c = 0; c < CO; ++c) {
          const float* wp = w + ((size_t)(co0 + c) * Cin + cig) * 9;
#pragma unroll
          for (int ky = 0; ky < 3; ++ky) {
#pragma unroll
            for (int kx = 0; kx < 3; ++kx) {
              float wv = wp[ky * 3 + kx];
              acc[c][0] = fmaf(wv, rin[ky][kx], acc[c][0]);
              acc[c][1] = fmaf(wv, rin[ky][kx + 1], acc[c][1]);
              acc[c][2] = fmaf(wv, rin[ky][kx + 2], acc[c][2]);
            }
          }
        }
      }
    }
  }
#pragma unroll
  for (int c = 0; c < CO; ++c) {
    float bv = bias[co0 + c];
    size_t o = (((size_t)b * Cout + co0 + c) * H + oy) * W + ox;
#pragma unroll
    for (int pimg = 0; pimg < 3; ++pimg) {
      float v = acc[c][pimg] + bv;
      if (ACT == 2) v = 1.0f / (1.0f + expf(-v));
      out[o + pimg] = v;
    }
  }
}

// ===== InstanceNorm (biased var, eps 1e-5) + optional ReLU, in place; block per (b,c) =====
__global__ __launch_bounds__(TPB) void inorm_relu_kernel(float* __restrict__ x, int N, int relu) {
  __shared__ float red[4];
  float* p = x + (size_t)blockIdx.x * N;
  int tid = threadIdx.x;
  float s = 0.f;
  for (int i = tid; i < N; i += TPB) s += p[i];
  s = wave_sum64(s);
  if ((tid & 63) == 0) red[tid >> 6] = s;
  __syncthreads();
  float mean = (red[0] + red[1] + red[2] + red[3]) / (float)N;
  __syncthreads();
  float v = 0.f;
  for (int i = tid; i < N; i += TPB) {
    float d = p[i] - mean;
    v = fmaf(d, d, v);
  }
  v = wave_sum64(v);
  if ((tid & 63) == 0) red[tid >> 6] = v;
  __syncthreads();
  float var = (red[0] + red[1] + red[2] + red[3]) / (float)N;
  float inv = 1.0f / sqrtf(var + 1e-5f);
  for (int i = tid; i < N; i += TPB) {
    float t = (p[i] - mean) * inv;
    if (relu) t = fmaxf(t, 0.f);
    p[i] = t;
  }
}

// ===== bilinear resize, align_corners=True =====
__global__ __launch_bounds__(TPB) void resize_ac_kernel(const float* __restrict__ in,
                                                        float* __restrict__ out, int BC,
                                                        int h, int w, int H, int W,
                                                        float ry, float rx) {
  int total = BC * H * W;
  for (int idx = blockIdx.x * TPB + threadIdx.x; idx < total; idx += gridDim.x * TPB) {
    int bc = idx / (H * W), r = idx - bc * (H * W);
    int Y = r / W, X = r - Y * W;
    float ys = Y * ry, xs = X * rx;
    int y0 = (int)floorf(ys);
    y0 = y0 < 0 ? 0 : (y0 > h - 1 ? h - 1 : y0);
    int x0 = (int)floorf(xs);
    x0 = x0 < 0 ? 0 : (x0 > w - 1 ? w - 1 : x0);
    int y1 = y0 + 1 < h ? y0 + 1 : h - 1;
    int x1 = x0 + 1 < w ? x0 + 1 : w - 1;
    float wy = ys - (float)y0, wx = xs - (float)x0;
    const float* ip = in + (size_t)bc * h * w;
    float a = ip[(size_t)y0 * w + x0], b2 = ip[(size_t)y0 * w + x1];
    float c = ip[(size_t)y1 * w + x0], d = ip[(size_t)y1 * w + x1];
    float top = a * (1.f - wy) + c * wy;
    float bot = b2 * (1.f - wy) + d * wy;
    out[idx] = top * (1.f - wx) + bot * wx;
  }
}

__global__ __launch_bounds__(TPB) void add_kernel(float* __restrict__ dst,
                                                  const float* __restrict__ src, int n) {
  int i = blockIdx.x * TPB + threadIdx.x;
  if (i < n) dst[i] += src[i];
}

extern "C" void kernel_launch(void* const* d_in, const int* in_sizes, int n_in,
                              void* d_out, int out_size, void* d_ws, size_t ws_size,
                              hipStream_t stream) {
  (void)in_sizes; (void)n_in; (void)out_size;
  const float* p3 = (const float*)d_in[0];
  const float* p2 = (const float*)d_in[1];
  const float* p1 = (const float*)d_in[2];
  const float* kg1 = (const float*)d_in[3];
  const float* klp = (const float*)d_in[4];
  const float* key_mask = (const float*)d_in[5];
  const float* pre_mask = (const float*)d_in[6];
  const float* conv_top_w = (const float*)d_in[7];
  const float* conv_top_b = (const float*)d_in[8];
  const float* aic_top_w1 = (const float*)d_in[9];
  const float* aic_top_b1 = (const float*)d_in[10];
  const float* aic_top_w2 = (const float*)d_in[11];
  const float* aic_top_b2 = (const float*)d_in[12];
  const float* r1a_w1 = (const float*)d_in[13];
  const float* r1a_b1 = (const float*)d_in[14];
  const float* r1a_w2 = (const float*)d_in[15];
  const float* r1a_b2 = (const float*)d_in[16];
  const float* r1b_w1 = (const float*)d_in[17];
  const float* r1b_b1 = (const float*)d_in[18];
  const float* r1b_w2 = (const float*)d_in[19];
  const float* r1b_b2 = (const float*)d_in[20];
  const float* r2a_w1 = (const float*)d_in[21];
  const float* r2a_b1 = (const float*)d_in[22];
  const float* r2a_w2 = (const float*)d_in[23];
  const float* r2a_b2 = (const float*)d_in[24];
  const float* r2b_w1 = (const float*)d_in[25];
  const float* r2b_b1 = (const float*)d_in[26];
  const float* r2b_w2 = (const float*)d_in[27];
  const float* r2b_b2 = (const float*)d_in[28];
  const float* dec_w = (const float*)d_in[29];
  const float* dec_b = (const float*)d_in[30];
  const float* pred_w = (const float*)d_in[31];
  const float* pred_b = (const float*)d_in[32];
  float* outp = (float*)d_out;

  // workspace layout (floats)
  const size_t OFF_GM = 0;              // 4608
  const size_t OFF_LM = 4608;           // 4608
  const size_t OFF_XCAT = 9216;         // 5,902,848
  const size_t OFF_A0 = 5912064;        // 1,179,648
  const size_t OFF_A1 = 7091712;        // 1,179,648
  const size_t OFF_H48 = 8271360;       // 294,912
  const size_t OFF_YB = 8566272;        // 4,718,592
  const size_t OFF_H96 = 13284864;      // 589,824
  const size_t OFF_D96 = 13874688;      // 589,824
  const size_t TOTAL_F = 14464512;      // ~55.2 MiB
  if (ws_size < TOTAL_F * sizeof(float)) return;  // insufficient scratch

  float* ws = (float*)d_ws;
  float* gm = ws + OFF_GM;
  float* lm = ws + OFF_LM;
  float* xcat = ws + OFF_XCAT;
  float* a0 = ws + OFF_A0;
  float* a1 = ws + OFF_A1;
  float* h48 = ws + OFF_H48;
  float* yB = ws + OFF_YB;
  float* h96 = ws + OFF_H96;
  float* d96 = ws + OFF_D96;
  float* yA = xcat;   // alias: xcat dead after conv_top
  float* zA = yB;     // alias: yB dead after r1b conv1
  float* zH = xcat;   // alias: yA dead after dec_conv1

  const int B = 2;
  // masks -> pooled
  pool8_kernel<<<(2 * 2304 + TPB - 1) / TPB, TPB, 0, stream>>>(key_mask, gm, 2 * 2304);
  pool8_kernel<<<(2 * 2304 + TPB - 1) / TPB, TPB, 0, stream>>>(pre_mask, lm, 2 * 2304);
  // correlation top-k -> xcat channels
  topk_global_kernel<<<2 * 2304, TPB, 0, stream>>>(kg1, gm, xcat);
  topk_local_kernel<<<2 * 2304, TPB, 0, stream>>>(klp, lm, xcat);
  copy_p3_kernel<<<(2 * 256 * 2304 + TPB - 1) / TPB, TPB, 0, stream>>>(p3, xcat);
  copy_pm_kernel<<<(2 * 2304 + TPB - 1) / TPB, TPB, 0, stream>>>(lm, xcat);

  auto conv = [&](const float* in, const float* w, const float* bb, float* out,
                  int Cin, int Cout, int H, int W) {
    dim3 grid((W / 48) * (H / 16), Cout / 4, B);
    conv3x3_kernel<4, 0><<<grid, TPB, 0, stream>>>(in, w, bb, out, Cin, Cout, H, W);
  };
  auto inorm = [&](float* x, int C, int N) {
    inorm_relu_kernel<<<B * C, TPB, 0, stream>>>(x, N, 1);
  };

  // top fuse @48
  conv(xcat, conv_top_w, conv_top_b, a0, 1281, 256, 48, 48);
  conv(a0, aic_top_w1, aic_top_b1, h48, 256, 64, 48, 48);
  inorm(h48, 64, 2304);
  conv(h48, aic_top_w2, aic_top_b2, a1, 64, 256, 48, 48);
  inorm(a1, 256, 2304);

  // 48 -> 96
  {
    float ry = (float)((48.0 - 1.0) / (96.0 - 1.0));
    int total = B * 256 * 96 * 96;
    resize_ac_kernel<<<(total + TPB - 1) / TPB, TPB, 0, stream>>>(a1, yA, B * 256, 48, 48, 96, 96, ry, ry);
  }
  conv(yA, r1a_w1, r1a_b1, h96, 256, 64, 96, 96);
  inorm(h96, 64, 9216);
  conv(h96, r1a_w2, r1a_b2, yB, 64, 256, 96, 96);
  inorm(yB, 256, 9216);
  add_kernel<<<(B * 256 * 9216 + TPB - 1) / TPB, TPB, 0, stream>>>(yB, p2, B * 256 * 9216);
  conv(yB, r1b_w1, r1b_b1, h96, 256, 64, 96, 96);
  inorm(h96, 64, 9216);
  conv(h96, r1b_w2, r1b_b2, yA, 64, 256, 96, 96);
  inorm(yA, 256, 9216);
  conv(yA, dec_w, dec_b, d96, 256, 64, 96, 96);

  // 96 -> 192
  {
    float ry = (float)((96.0 - 1.0) / (192.0 - 1.0));
    int total = B * 64 * 192 * 192;
    resize_ac_kernel<<<(total + TPB - 1) / TPB, TPB, 0, stream>>>(d96, zA, B * 64, 96, 96, 192, 192, ry, ry);
  }
  conv(zA, r2a_w1, r2a_b1, zH, 64, 64, 192, 192);
  inorm(zH, 64, 36864);
  conv(zH, r2a_w2, r2a_b2, zA, 64, 64, 192, 192);
  inorm(zA, 64, 36864);
  add_kernel<<<(B * 64 * 36864 + TPB - 1) / TPB, TPB, 0, stream>>>(zA, p1, B * 64 * 36864);
  conv(zA, r2b_w1, r2b_b1, zH, 64, 64, 192, 192);
  inorm(zH, 64, 36864);
  conv(zH, r2b_w2, r2b_b2, zA, 64, 64, 192, 192);
  inorm(zA, 64, 36864);

  // pred head: 64 -> 1 + sigmoid -> d_out
  {
    dim3 grid((192 / 48) * (192 / 16), 1, B);
    conv3x3_kernel<1, 2><<<grid, TPB, 0, stream>>>(zA, pred_w, pred_b, outp, 64, 1, 192, 192);
  }
}

// Round 2
// 3276.896 us; speedup vs baseline: 2.2830x; 2.2830x over previous
//
#include <hip/hip_runtime.h>
#include <math.h>

#define TPB 256

typedef short bh8 __attribute__((ext_vector_type(8)));
typedef float f4 __attribute__((ext_vector_type(4)));

__device__ __forceinline__ unsigned short f2bf(float x) {
  unsigned int u = __float_as_uint(x);
  unsigned int r = (u + 0x7fffu + ((u >> 16) & 1u)) >> 16;
  return (unsigned short)r;
}
__device__ __forceinline__ float bf2f(unsigned short h) {
  return __uint_as_float(((unsigned int)h) << 16);
}

__device__ __forceinline__ float wave_sum64(float v) {
#pragma unroll
  for (int o = 32; o > 0; o >>= 1) v += __shfl_down(v, o, 64);
  return v;
}

// ===== 8x8 max pool: [B,1,384,384] -> [B,2304] =====
__global__ __launch_bounds__(TPB) void pool8_kernel(const float* __restrict__ in,
                                                    float* __restrict__ out, int total) {
  int idx = blockIdx.x * TPB + threadIdx.x;
  if (idx >= total) return;
  int b = idx / 2304, yx = idx - b * 2304;
  int y = yx / 48, x = yx - y * 48;
  const float* p = in + ((size_t)b * 384 + (size_t)y * 8) * 384 + (size_t)x * 8;
  float m = -INFINITY;
#pragma unroll
  for (int i = 0; i < 8; ++i) {
#pragma unroll
    for (int j = 0; j < 8; ++j) m = fmaxf(m, p[(size_t)i * 384 + j]);
  }
  out[idx] = m;
}

// ===== bitonic ascending sort of N (power of 2) floats in LDS, 256 threads =====
template <int N>
__device__ void bitonic_sort_asc(float* s) {
  for (int k = 2; k <= N; k <<= 1) {
    for (int j = k >> 1; j > 0; j >>= 1) {
      __syncthreads();
      for (int t = threadIdx.x; t < N; t += TPB) {
        int ixj = t ^ j;
        if (ixj > t) {
          float a = s[t], b = s[ixj];
          bool up = ((t & k) == 0);
          bool sw = up ? (a > b) : (a < b);
          if (sw) { s[t] = b; s[ixj] = a; }
        }
      }
    }
  }
  __syncthreads();
}

__global__ __launch_bounds__(TPB) void topk_global_kernel(const float* __restrict__ kg1,
                                                          const float* __restrict__ gm,
                                                          float* __restrict__ xcat) {
  __shared__ float sf[4096];
  __shared__ float sb[4096];
  int bid = blockIdx.x;
  int b = bid / 2304, yx = bid - b * 2304;
  const float* kp = kg1 + (size_t)b * 2304 * 2304 + yx;
  const float* gp = gm + (size_t)b * 2304;
  for (int i = threadIdx.x; i < 4096; i += TPB) {
    float vf = -INFINITY, vb = -INFINITY;
    if (i < 2304) {
      float v = kp[(size_t)i * 2304];
      float g = gp[i];
      vf = v * g;
      vb = v * (1.0f - g);
    }
    sf[i] = vf;
    sb[i] = vb;
  }
  bitonic_sort_asc<4096>(sf);
  xcat[((size_t)b * 1281 + 256 + threadIdx.x) * 2304 + yx] = sf[4095 - threadIdx.x];
  bitonic_sort_asc<4096>(sb);
  xcat[((size_t)b * 1281 + 512 + threadIdx.x) * 2304 + yx] = sb[4095 - threadIdx.x];
}

__global__ __launch_bounds__(TPB) void topk_local_kernel(const float* __restrict__ klp,
                                                         const float* __restrict__ lm,
                                                         float* __restrict__ xcat) {
  __shared__ float sf[512];
  __shared__ float sb[512];
  int bid = blockIdx.x;
  int b = bid / 2304, yx = bid - b * 2304;
  int y = yx / 48, x = yx - y * 48;
  for (int i = threadIdx.x; i < 512; i += TPB) {
    float vf = -INFINITY, vb = -INFINITY;
    if (i < 289) {
      int dy = i / 17, dx = i - dy * 17;
      int sy = y + dy - 8, sx = x + dx - 8;
      float pv = 0.f;
      if (sy >= 0 && sy < 48 && sx >= 0 && sx < 48) pv = lm[(size_t)b * 2304 + sy * 48 + sx];
      float v = klp[((size_t)b * 289 + i) * 2304 + yx];
      vf = v * pv;
      vb = v * (1.0f - pv);
    }
    sf[i] = vf;
    sb[i] = vb;
  }
  bitonic_sort_asc<512>(sf);
  xcat[((size_t)b * 1281 + 768 + threadIdx.x) * 2304 + yx] = sf[511 - threadIdx.x];
  bitonic_sort_asc<512>(sb);
  xcat[((size_t)b * 1281 + 1024 + threadIdx.x) * 2304 + yx] = sb[511 - threadIdx.x];
}

__global__ __launch_bounds__(TPB) void copy_p3_kernel(const float* __restrict__ p3,
                                                      float* __restrict__ xcat) {
  int idx = blockIdx.x * TPB + threadIdx.x;
  const int per_b = 256 * 2304;
  if (idx >= 2 * per_b) return;
  int b = idx / per_b, r = idx - b * per_b;
  xcat[(size_t)b * 1281 * 2304 + r] = p3[idx];
}

__global__ __launch_bounds__(TPB) void copy_pm_kernel(const float* __restrict__ lm,
                                                      float* __restrict__ xcat) {
  int idx = blockIdx.x * TPB + threadIdx.x;
  if (idx >= 2 * 2304) return;
  int b = idx / 2304, yx = idx - b * 2304;
  xcat[((size_t)b * 1281 + 1280) * 2304 + yx] = lm[idx];
}

// ===== weight preconvert: OIHW fp32 -> Wb[co][kykx][cipad] split bf16 (hi, lo) =====
__global__ __launch_bounds__(TPB) void wconv_kernel(const float* __restrict__ w,
                                                    unsigned short* __restrict__ whi,
                                                    unsigned short* __restrict__ wlo,
                                                    int Cin, int cipad, int total) {
  int i = blockIdx.x * TPB + threadIdx.x;
  if (i >= total) return;
  int ci = i % cipad;
  int rest = i / cipad;
  int kk = rest % 9;
  int co = rest / 9;
  float v = 0.f;
  if (ci < Cin) v = w[((size_t)co * Cin + ci) * 9 + kk];
  unsigned short h = f2bf(v);
  whi[i] = h;
  wlo[i] = f2bf(v - bf2f(h));
}

// ===== MFMA implicit-GEMM 3x3 conv, split-bf16 (3-term) fp32 accumulate =====
// Block: 256 thr = 4 waves; output tile 64 co x 64 px (8x8 spatial); halo 10x10 in LDS.
// gridDim = (tilesX*tilesY, (Cout/64)*S, B). S>1 -> write fp32 partials, reduce adds bias.
__global__ __launch_bounds__(TPB) void conv_mfma_kernel(
    const float* __restrict__ in, const unsigned short* __restrict__ whi,
    const unsigned short* __restrict__ wlo, const float* __restrict__ bias,
    float* __restrict__ outp, float* __restrict__ partial,
    int Cin, int cipad, int Cout, int H, int W, int S, int ci_per_s) {
  __shared__ uint2 sbh[900];  // [100 pix][stride 18 words] bf16-hi, 32 ci per pix
  __shared__ uint2 sbl[900];  // bf16-lo
  const int tid = threadIdx.x;
  const int lane = tid & 63, wid = tid >> 6;
  const int lo16 = lane & 15, hi4 = lane >> 4;
  const int wco = wid & 1, wpx = wid >> 1;
  const int tilesX = W >> 3;
  const int tx0 = (blockIdx.x % tilesX) << 3;
  const int ty0 = (blockIdx.x / tilesX) << 3;
  const int s = blockIdx.y % S;
  const int co0 = (blockIdx.y / S) * 64;
  const int b = blockIdx.z;
  const size_t HW = (size_t)H * W;
  const float* inb = in + (size_t)b * Cin * HW;
  int ci_begin = s * ci_per_s;
  int ci_end = ci_begin + ci_per_s;
  if (ci_end > cipad) ci_end = cipad;
  f4 acc[2][2];
#pragma unroll
  for (int m = 0; m < 2; ++m)
#pragma unroll
    for (int n = 0; n < 2; ++n) acc[m][n] = (f4){0.f, 0.f, 0.f, 0.f};
  const int trow0 = wpx * 4 + (lo16 >> 3);
  const int tcol0 = lo16 & 7;

  for (int ci0 = ci_begin; ci0 < ci_end; ci0 += 32) {
    __syncthreads();
    for (int u = tid; u < 1600; u += TPB) {
      int c2 = u / 100;
      int pix = u - c2 * 100;
      int prow = pix / 10;
      int pcol = pix - prow * 10;
      int gy = ty0 - 1 + prow, gx = tx0 - 1 + pcol;
      int ci = ci0 + c2 * 2;
      float v0 = 0.f, v1 = 0.f;
      if (gy >= 0 && gy < H && gx >= 0 && gx < W) {
        const float* q = inb + (size_t)ci * HW + (size_t)gy * W + gx;
        if (ci < Cin) v0 = q[0];
        if (ci + 1 < Cin) v1 = q[HW];
      }
      unsigned short h0 = f2bf(v0), h1 = f2bf(v1);
      unsigned int ph = (unsigned int)h0 | ((unsigned int)h1 << 16);
      unsigned int pl = (unsigned int)f2bf(v0 - bf2f(h0)) |
                        ((unsigned int)f2bf(v1 - bf2f(h1)) << 16);
      ((unsigned int*)sbh)[pix * 18 + c2] = ph;
      ((unsigned int*)sbl)[pix * 18 + c2] = pl;
    }
    __syncthreads();
#pragma unroll
    for (int ky = 0; ky < 3; ++ky) {
#pragma unroll
      for (int kx = 0; kx < 3; ++kx) {
        bh8 bh[2], bl[2];
#pragma unroll
        for (int n = 0; n < 2; ++n) {
          int pix = (trow0 + n * 2 + ky) * 10 + tcol0 + kx;
          int pq = pix * 9 + 2 * hi4;
          union { uint2 q[2]; bh8 v; } ub;
          ub.q[0] = sbh[pq];
          ub.q[1] = sbh[pq + 1];
          bh[n] = ub.v;
          union { uint2 q[2]; bh8 v; } ul;
          ul.q[0] = sbl[pq];
          ul.q[1] = sbl[pq + 1];
          bl[n] = ul.v;
        }
        int kykx = ky * 3 + kx;
#pragma unroll
        for (int m = 0; m < 2; ++m) {
          size_t woff = ((size_t)(co0 + wco * 32 + m * 16 + lo16) * 9 + kykx) * cipad +
                        ci0 + 8 * hi4;
          bh8 ah = *(const bh8*)(whi + woff);
          bh8 al = *(const bh8*)(wlo + woff);
#pragma unroll
          for (int n = 0; n < 2; ++n) {
            acc[m][n] = __builtin_amdgcn_mfma_f32_16x16x32_bf16(ah, bh[n], acc[m][n], 0, 0, 0);
            acc[m][n] = __builtin_amdgcn_mfma_f32_16x16x32_bf16(ah, bl[n], acc[m][n], 0, 0, 0);
            acc[m][n] = __builtin_amdgcn_mfma_f32_16x16x32_bf16(al, bh[n], acc[m][n], 0, 0, 0);
          }
        }
      }
    }
  }

#pragma unroll
  for (int m = 0; m < 2; ++m) {
    int co_r0 = co0 + wco * 32 + m * 16 + hi4 * 4;
#pragma unroll
    for (int n = 0; n < 2; ++n) {
      int py = ty0 + wpx * 4 + n * 2 + (lo16 >> 3);
      int px = tx0 + tcol0;
#pragma unroll
      for (int r = 0; r < 4; ++r) {
        int co_r = co_r0 + r;
        float v = acc[m][n][r];
        if (S == 1) {
          v += bias[co_r];
          outp[(size_t)(b * Cout + co_r) * HW + (size_t)py * W + px] = v;
        } else {
          partial[((size_t)(s * 2 + b) * Cout + co_r) * HW + (size_t)py * W + px] = v;
        }
      }
    }
  }
}

// ===== split-K reduce + bias =====
__global__ __launch_bounds__(TPB) void reduce_bias_kernel(const float* __restrict__ partial,
                                                          const float* __restrict__ bias,
                                                          float* __restrict__ outp, int S,
                                                          int Cout, int HW, int total4) {
  int i = blockIdx.x * TPB + threadIdx.x;
  if (i >= total4) return;
  int e = i * 4;
  int chw = Cout * HW;
  int b = e / chw;
  int rem = e - b * chw;
  int co = rem / HW;
  float4 acc = {0.f, 0.f, 0.f, 0.f};
  for (int ss = 0; ss < S; ++ss) {
    const float4 t = *(const float4*)(partial + (size_t)(ss * 2 + b) * chw + rem);
    acc.x += t.x; acc.y += t.y; acc.z += t.z; acc.w += t.w;
  }
  float bv = bias[co];
  float4 o = {acc.x + bv, acc.y + bv, acc.z + bv, acc.w + bv};
  *(float4*)(outp + (size_t)b * chw + rem) = o;
}

// ===== fp32 direct 3x3 conv (kept for pred head 64->1 + sigmoid) =====
template <int CO, int ACT>
__global__ __launch_bounds__(TPB) void conv3x3_kernel(
    const float* __restrict__ in, const float* __restrict__ w,
    const float* __restrict__ bias, float* __restrict__ out,
    int Cin, int Cout, int H, int W) {
  const int CIC = 4;
  __shared__ float sin_t[CIC][18 * 50];
  int tid = threadIdx.x;
  int tx = tid & 15, ty = tid >> 4;
  int tilesX = W / 48;
  int bx = blockIdx.x % tilesX, by = blockIdx.x / tilesX;
  int co0 = blockIdx.y * CO;
  int b = blockIdx.z;
  int oy = by * 16 + ty;
  int ox = bx * 48 + tx * 3;
  float acc[CO][3];
#pragma unroll
  for (int c = 0; c < CO; ++c) { acc[c][0] = acc[c][1] = acc[c][2] = 0.f; }
  int gy0 = by * 16 - 1, gx0 = bx * 48 - 1;
  const size_t in_b = (size_t)b * Cin * H * W;
  for (int ci0 = 0; ci0 < Cin; ci0 += CIC) {
    __syncthreads();
    for (int idx = tid; idx < CIC * 900; idx += TPB) {
      int ci = idx / 900, r = idx - ci * 900;
      int row = r / 50, col = r - row * 50;
      int gy = gy0 + row, gx = gx0 + col;
      int cig = ci0 + ci;
      float v = 0.f;
      if (cig < Cin && gy >= 0 && gy < H && gx >= 0 && gx < W)
        v = in[in_b + ((size_t)cig * H + gy) * W + gx];
      sin_t[ci][r] = v;
    }
    __syncthreads();
#pragma unroll
    for (int ci = 0; ci < CIC; ++ci) {
      int cig = ci0 + ci;
      if (cig < Cin) {
        float rin[3][5];
        const float* sp = &sin_t[ci][ty * 50 + tx * 3];
#pragma unroll
        for (int d = 0; d < 5; ++d) {
          rin[0][d] = sp[d];
          rin[1][d] = sp[50 + d];
          rin[2][d] = sp[100 + d];
        }
#pragma unroll
        for (int c = 0; c < CO; ++c) {
          const float* wp = w + ((size_t)(co0 + c) * Cin + cig) * 9;
#pragma unroll
          for (int ky = 0; ky < 3; ++ky) {
#pragma unroll
            for (int kx = 0; kx < 3; ++kx) {
              float wv = wp[ky * 3 + kx];
              acc[c][0] = fmaf(wv, rin[ky][kx], acc[c][0]);
              acc[c][1] = fmaf(wv, rin[ky][kx + 1], acc[c][1]);
              acc[c][2] = fmaf(wv, rin[ky][kx + 2], acc[c][2]);
            }
          }
        }
      }
    }
  }
#pragma unroll
  for (int c = 0; c < CO; ++c) {
    float bv = bias[co0 + c];
    size_t o = (((size_t)b * Cout + co0 + c) * H + oy) * W + ox;
#pragma unroll
    for (int pimg = 0; pimg < 3; ++pimg) {
      float v = acc[c][pimg] + bv;
      if (ACT == 2) v = 1.0f / (1.0f + expf(-v));
      out[o + pimg] = v;
    }
  }
}

// ===== InstanceNorm (biased var, eps 1e-5) + ReLU, in place; block per (b,c) =====
__global__ __launch_bounds__(TPB) void inorm_relu_kernel(float* __restrict__ x, int N, int relu) {
  __shared__ float red[4];
  float* p = x + (size_t)blockIdx.x * N;
  int tid = threadIdx.x;
  float s = 0.f;
  for (int i = tid; i < N; i += TPB) s += p[i];
  s = wave_sum64(s);
  if ((tid & 63) == 0) red[tid >> 6] = s;
  __syncthreads();
  float mean = (red[0] + red[1] + red[2] + red[3]) / (float)N;
  __syncthreads();
  float v = 0.f;
  for (int i = tid; i < N; i += TPB) {
    float d = p[i] - mean;
    v = fmaf(d, d, v);
  }
  v = wave_sum64(v);
  if ((tid & 63) == 0) red[tid >> 6] = v;
  __syncthreads();
  float var = (red[0] + red[1] + red[2] + red[3]) / (float)N;
  float inv = 1.0f / sqrtf(var + 1e-5f);
  for (int i = tid; i < N; i += TPB) {
    float t = (p[i] - mean) * inv;
    if (relu) t = fmaxf(t, 0.f);
    p[i] = t;
  }
}

__global__ __launch_bounds__(TPB) void resize_ac_kernel(const float* __restrict__ in,
                                                        float* __restrict__ out, int BC,
                                                        int h, int w, int H, int W,
                                                        float ry, float rx) {
  int total = BC * H * W;
  for (int idx = blockIdx.x * TPB + threadIdx.x; idx < total; idx += gridDim.x * TPB) {
    int bc = idx / (H * W), r = idx - bc * (H * W);
    int Y = r / W, X = r - Y * W;
    float ys = Y * ry, xs = X * rx;
    int y0 = (int)floorf(ys);
    y0 = y0 < 0 ? 0 : (y0 > h - 1 ? h - 1 : y0);
    int x0 = (int)floorf(xs);
    x0 = x0 < 0 ? 0 : (x0 > w - 1 ? w - 1 : x0);
    int y1 = y0 + 1 < h ? y0 + 1 : h - 1;
    int x1 = x0 + 1 < w ? x0 + 1 : w - 1;
    float wy = ys - (float)y0, wx = xs - (float)x0;
    const float* ip = in + (size_t)bc * h * w;
    float a = ip[(size_t)y0 * w + x0], b2 = ip[(size_t)y0 * w + x1];
    float c = ip[(size_t)y1 * w + x0], d = ip[(size_t)y1 * w + x1];
    float top = a * (1.f - wy) + c * wy;
    float bot = b2 * (1.f - wy) + d * wy;
    out[idx] = top * (1.f - wx) + bot * wx;
  }
}

__global__ __launch_bounds__(TPB) void add_kernel(float* __restrict__ dst,
                                                  const float* __restrict__ src, int n) {
  int i = blockIdx.x * TPB + threadIdx.x;
  if (i < n) dst[i] += src[i];
}

extern "C" void kernel_launch(void* const* d_in, const int* in_sizes, int n_in,
                              void* d_out, int out_size, void* d_ws, size_t ws_size,
                              hipStream_t stream) {
  (void)in_sizes; (void)n_in; (void)out_size;
  const float* p3 = (const float*)d_in[0];
  const float* p2 = (const float*)d_in[1];
  const float* p1 = (const float*)d_in[2];
  const float* kg1 = (const float*)d_in[3];
  const float* klp = (const float*)d_in[4];
  const float* key_mask = (const float*)d_in[5];
  const float* pre_mask = (const float*)d_in[6];
  const float* conv_top_w = (const float*)d_in[7];
  const float* conv_top_b = (const float*)d_in[8];
  const float* aic_top_w1 = (const float*)d_in[9];
  const float* aic_top_b1 = (const float*)d_in[10];
  const float* aic_top_w2 = (const float*)d_in[11];
  const float* aic_top_b2 = (const float*)d_in[12];
  const float* r1a_w1 = (const float*)d_in[13];
  const float* r1a_b1 = (const float*)d_in[14];
  const float* r1a_w2 = (const float*)d_in[15];
  const float* r1a_b2 = (const float*)d_in[16];
  const float* r1b_w1 = (const float*)d_in[17];
  const float* r1b_b1 = (const float*)d_in[18];
  const float* r1b_w2 = (const float*)d_in[19];
  const float* r1b_b2 = (const float*)d_in[20];
  const float* r2a_w1 = (const float*)d_in[21];
  const float* r2a_b1 = (const float*)d_in[22];
  const float* r2a_w2 = (const float*)d_in[23];
  const float* r2a_b2 = (const float*)d_in[24];
  const float* r2b_w1 = (const float*)d_in[25];
  const float* r2b_b1 = (const float*)d_in[26];
  const float* r2b_w2 = (const float*)d_in[27];
  const float* r2b_b2 = (const float*)d_in[28];
  const float* dec_w = (const float*)d_in[29];
  const float* dec_b = (const float*)d_in[30];
  const float* pred_w = (const float*)d_in[31];
  const float* pred_b = (const float*)d_in[32];
  float* outp = (float*)d_out;

  // workspace layout (float units)
  const size_t OFF_GM = 0;               // 4608
  const size_t OFF_LM = 4608;            // 4608
  const size_t OFF_XCAT = 9216;          // 5,902,848 (also yA @96, zH @192)
  const size_t OFF_A0 = 5912064;         // 1,179,648
  const size_t OFF_A1 = 7091712;         // 1,179,648
  const size_t OFF_H48 = 8271360;        // 294,912
  const size_t OFF_YB = 8566272;         // 4,718,592 (also zA @192)
  const size_t OFF_H96 = 13284864;       // 1,179,648
  const size_t OFF_D96 = 14464512;       // 1,179,648
  const size_t OFF_P = 15644160;         // 4,718,592 split-K partials
  const size_t OFF_WB = 20362752;        // 3,022,848 floats = 6,045,696 ushort (hi+lo)
  const size_t TOTAL_F = 23385600;       // ~93.6 MiB
  if (ws_size < TOTAL_F * sizeof(float)) return;

  float* ws = (float*)d_ws;
  float* gm = ws + OFF_GM;
  float* lm = ws + OFF_LM;
  float* xcat = ws + OFF_XCAT;
  float* a0 = ws + OFF_A0;
  float* a1 = ws + OFF_A1;
  float* h48 = ws + OFF_H48;
  float* yB = ws + OFF_YB;
  float* h96 = ws + OFF_H96;
  float* d96 = ws + OFF_D96;
  float* Pbuf = ws + OFF_P;
  unsigned short* wbh = (unsigned short*)(ws + OFF_WB);
  const size_t WHALF = 3022848;  // ushort capacity per half (= conv_top's 256*9*1312)
  unsigned short* wbl = wbh + WHALF;
  float* yA = xcat;
  float* zA = yB;
  float* zH = xcat;

  pool8_kernel<<<(2 * 2304 + TPB - 1) / TPB, TPB, 0, stream>>>(key_mask, gm, 2 * 2304);
  pool8_kernel<<<(2 * 2304 + TPB - 1) / TPB, TPB, 0, stream>>>(pre_mask, lm, 2 * 2304);
  topk_global_kernel<<<2 * 2304, TPB, 0, stream>>>(kg1, gm, xcat);
  topk_local_kernel<<<2 * 2304, TPB, 0, stream>>>(klp, lm, xcat);
  copy_p3_kernel<<<(2 * 256 * 2304 + TPB - 1) / TPB, TPB, 0, stream>>>(p3, xcat);
  copy_pm_kernel<<<(2 * 2304 + TPB - 1) / TPB, TPB, 0, stream>>>(lm, xcat);

  auto run_conv = [&](const float* src, const float* w, const float* bb, float* dst,
                      int Cin, int Cout, int H, int W, int S) {
    int cipad = (Cin + 31) & ~31;
    int wtotal = Cout * 9 * cipad;
    wconv_kernel<<<(wtotal + TPB - 1) / TPB, TPB, 0, stream>>>(w, wbh, wbl, Cin, cipad, wtotal);
    int chunks = cipad / 32;
    int cps = ((chunks + S - 1) / S) * 32;
    dim3 grid((W / 8) * (H / 8), (Cout / 64) * S, 2);
    conv_mfma_kernel<<<grid, TPB, 0, stream>>>(src, wbh, wbl, bb, dst, Pbuf, Cin, cipad,
                                               Cout, H, W, S, cps);
    if (S > 1) {
      int HW = H * W;
      int total4 = 2 * Cout * HW / 4;
      reduce_bias_kernel<<<(total4 + TPB - 1) / TPB, TPB, 0, stream>>>(Pbuf, bb, dst, S,
                                                                       Cout, HW, total4);
    }
  };
  auto inorm = [&](float* x, int C, int N) {
    inorm_relu_kernel<<<2 * C, TPB, 0, stream>>>(x, N, 1);
  };

  // top fuse @48
  run_conv(xcat, conv_top_w, conv_top_b, a0, 1281, 256, 48, 48, 4);
  run_conv(a0, aic_top_w1, aic_top_b1, h48, 256, 64, 48, 48, 8);
  inorm(h48, 64, 2304);
  run_conv(h48, aic_top_w2, aic_top_b2, a1, 64, 256, 48, 48, 2);
  inorm(a1, 256, 2304);

  // 48 -> 96
  {
    float ry = (float)((48.0 - 1.0) / (96.0 - 1.0));
    int total = 2 * 256 * 96 * 96;
    resize_ac_kernel<<<(total + TPB - 1) / TPB, TPB, 0, stream>>>(a1, yA, 2 * 256, 48, 48,
                                                                  96, 96, ry, ry);
  }
  run_conv(yA, r1a_w1, r1a_b1, h96, 256, 64, 96, 96, 4);
  inorm(h96, 64, 9216);
  run_conv(h96, r1a_w2, r1a_b2, yB, 64, 256, 96, 96, 1);
  inorm(yB, 256, 9216);
  add_kernel<<<(2 * 256 * 9216 + TPB - 1) / TPB, TPB, 0, stream>>>(yB, p2, 2 * 256 * 9216);
  run_conv(yB, r1b_w1, r1b_b1, h96, 256, 64, 96, 96, 4);
  inorm(h96, 64, 9216);
  run_conv(h96, r1b_w2, r1b_b2, yA, 64, 256, 96, 96, 1);
  inorm(yA, 256, 9216);
  run_conv(yA, dec_w, dec_b, d96, 256, 64, 96, 96, 4);

  // 96 -> 192
  {
    float ry = (float)((96.0 - 1.0) / (192.0 - 1.0));
    int total = 2 * 64 * 192 * 192;
    resize_ac_kernel<<<(total + TPB - 1) / TPB, TPB, 0, stream>>>(d96, zA, 2 * 64, 96, 96,
                                                                  192, 192, ry, ry);
  }
  run_conv(zA, r2a_w1, r2a_b1, zH, 64, 64, 192, 192, 1);
  inorm(zH, 64, 36864);
  run_conv(zH, r2a_w2, r2a_b2, zA, 64, 64, 192, 192, 1);
  inorm(zA, 64, 36864);
  add_kernel<<<(2 * 64 * 36864 + TPB - 1) / TPB, TPB, 0, stream>>>(zA, p1, 2 * 64 * 36864);
  run_conv(zA, r2b_w1, r2b_b1, zH, 64, 64, 192, 192, 1);
  inorm(zH, 64, 36864);
  run_conv(zH, r2b_w2, r2b_b2, zA, 64, 64, 192, 192, 1);
  inorm(zA, 64, 36864);

  // pred head: 64 -> 1 + sigmoid -> d_out
  {
    dim3 grid((192 / 48) * (192 / 16), 1, 2);
    conv3x3_kernel<1, 2><<<grid, TPB, 0, stream>>>(zA, pred_w, pred_b, outp, 64, 1, 192, 192);
  }
}

// Round 3
// 1747.665 us; speedup vs baseline: 4.2807x; 1.8750x over previous
//
#include <hip/hip_runtime.h>
#include <math.h>

#define TPB 256

typedef short bh8 __attribute__((ext_vector_type(8)));
typedef float f4 __attribute__((ext_vector_type(4)));

__device__ __forceinline__ unsigned short f2bf(float x) {
  unsigned int u = __float_as_uint(x);
  unsigned int r = (u + 0x7fffu + ((u >> 16) & 1u)) >> 16;
  return (unsigned short)r;
}
__device__ __forceinline__ float bf2f(unsigned short h) {
  return __uint_as_float(((unsigned int)h) << 16);
}

__device__ __forceinline__ unsigned key_of(float x) {
  unsigned u = __float_as_uint(x);
  return u ^ ((u >> 31) ? 0xFFFFFFFFu : 0x80000000u);
}
__device__ __forceinline__ float un_key(unsigned k) {
  unsigned u = k ^ ((k >> 31) ? 0x80000000u : 0xFFFFFFFFu);
  return __uint_as_float(u);
}

__device__ __forceinline__ float wave_sum64(float v) {
#pragma unroll
  for (int o = 32; o > 0; o >>= 1) v += __shfl_down(v, o, 64);
  return v;
}

// ===== 8x8 max pool: [B,1,384,384] -> [B,2304] =====
__global__ __launch_bounds__(TPB) void pool8_kernel(const float* __restrict__ in,
                                                    float* __restrict__ out, int total) {
  int idx = blockIdx.x * TPB + threadIdx.x;
  if (idx >= total) return;
  int b = idx / 2304, yx = idx - b * 2304;
  int y = yx / 48, x = yx - y * 48;
  const float* p = in + ((size_t)b * 384 + (size_t)y * 8) * 384 + (size_t)x * 8;
  float m = -INFINITY;
#pragma unroll
  for (int i = 0; i < 8; ++i) {
#pragma unroll
    for (int j = 0; j < 8; ++j) m = fmaxf(m, p[(size_t)i * 384 + j]);
  }
  out[idx] = m;
}

// ===== global top-k via 4-pass radix select + bitonic-256, both polarities =====
// block = one pixel; 2304 channels; keys live in registers (9 per thread per pol).
__global__ __launch_bounds__(TPB) void topk_global_kernel(const float* __restrict__ kg1,
                                                          const float* __restrict__ gm,
                                                          float* __restrict__ xcat) {
  __shared__ unsigned histF[256], histB[256];
  __shared__ unsigned soutF[256], soutB[256];
  __shared__ unsigned selT[2], selA[2];
  __shared__ unsigned cntG[2], cntE[2];
  const int tid = threadIdx.x;
  const int lane = tid & 63, wid = tid >> 6;
  int bid = blockIdx.x;
  int b = bid / 2304, yx = bid - b * 2304;
  const float* kp = kg1 + (size_t)b * 2304 * 2304 + yx;
  const float* gp = gm + (size_t)b * 2304;
  unsigned kF[9], kB[9];
#pragma unroll
  for (int j = 0; j < 9; ++j) {
    int i = tid + 256 * j;
    float v = kp[(size_t)i * 2304];
    float g = gp[i];
    kF[j] = key_of(v * g);
    kB[j] = key_of(v * (1.0f - g));
  }
  unsigned prefF = 0, prefB = 0;
  unsigned KF = 256, KB = 256;
  unsigned gtF = 0, gtB = 0;
#pragma unroll
  for (int p = 0; p < 4; ++p) {
    const int shift = 24 - 8 * p;
    histF[tid] = 0;
    histB[tid] = 0;
    __syncthreads();
#pragma unroll
    for (int j = 0; j < 9; ++j) {
      if (p == 0 || (kF[j] >> (shift + 8)) == prefF)
        atomicAdd(&histF[(kF[j] >> shift) & 0xFFu], 1u);
      if (p == 0 || (kB[j] >> (shift + 8)) == prefB)
        atomicAdd(&histB[(kB[j] >> shift) & 0xFFu], 1u);
    }
    __syncthreads();
    if (wid < 2) {
      unsigned* h = wid ? histB : histF;
      unsigned K = wid ? KB : KF;
      unsigned h0 = h[4 * lane], h1 = h[4 * lane + 1];
      unsigned h2 = h[4 * lane + 2], h3 = h[4 * lane + 3];
      unsigned loc = h0 + h1 + h2 + h3;
      unsigned x = loc;
#pragma unroll
      for (int d = 1; d < 64; d <<= 1) {
        unsigned y = __shfl_down(x, d, 64);
        if (lane + d < 64) x += y;
      }
      unsigned long long m = __ballot(x >= K);
      int tl = 63 - __clzll(m);
      if (lane == tl) {
        unsigned s1 = x - h0, s2 = s1 - h1, s3 = s2 - h2, s4 = s3 - h3;
        int jj;
        unsigned A;
        if (s3 >= K) { jj = 3; A = s4; }
        else if (s2 >= K) { jj = 2; A = s3; }
        else if (s1 >= K) { jj = 1; A = s2; }
        else { jj = 0; A = s1; }
        selT[wid] = 4 * tl + jj;
        selA[wid] = A;
      }
    }
    __syncthreads();
    unsigned TF = selT[0], AF = selA[0];
    unsigned TB = selT[1], AB = selA[1];
    prefF = (prefF << 8) | TF;
    gtF += AF;
    KF -= AF;
    prefB = (prefB << 8) | TB;
    gtB += AB;
    KB -= AB;
    __syncthreads();
  }
  const unsigned tF = prefF, tB = prefB;
  const unsigned nGTF = gtF, needF = KF;
  const unsigned nGTB = gtB, needB = KB;
  if (tid == 0) { cntG[0] = 0; cntG[1] = 0; cntE[0] = 0; cntE[1] = 0; }
  __syncthreads();
#pragma unroll
  for (int j = 0; j < 9; ++j) {
    unsigned k = kF[j];
    if (k > tF) {
      soutF[atomicAdd(&cntG[0], 1u)] = k;
    } else if (k == tF) {
      unsigned e = atomicAdd(&cntE[0], 1u);
      if (e < needF) soutF[nGTF + e] = tF;
    }
    k = kB[j];
    if (k > tB) {
      soutB[atomicAdd(&cntG[1], 1u)] = k;
    } else if (k == tB) {
      unsigned e = atomicAdd(&cntE[1], 1u);
      if (e < needB) soutB[nGTB + e] = tB;
    }
  }
  __syncthreads();
  // fused bitonic ascending sort of both 256-element key arrays
  for (int kk = 2; kk <= 256; kk <<= 1) {
    for (int j = kk >> 1; j > 0; j >>= 1) {
      int t = tid, ixj = t ^ j;
      if (ixj > t) {
        bool up = ((t & kk) == 0);
        unsigned a = soutF[t], c = soutF[ixj];
        if (up ? (a > c) : (a < c)) { soutF[t] = c; soutF[ixj] = a; }
        a = soutB[t];
        c = soutB[ixj];
        if (up ? (a > c) : (a < c)) { soutB[t] = c; soutB[ixj] = a; }
      }
      __syncthreads();
    }
  }
  float vf = un_key(soutF[255 - tid]);
  float vb = un_key(soutB[255 - tid]);
  xcat[((size_t)b * 1281 + 256 + tid) * 2304 + yx] = vf;
  xcat[((size_t)b * 1281 + 512 + tid) * 2304 + yx] = vb;
}

// ===== local top-k: full fused bitonic over 512-padded window (289 values) =====
__global__ __launch_bounds__(TPB) void topk_local_kernel(const float* __restrict__ klp,
                                                         const float* __restrict__ lm,
                                                         float* __restrict__ xcat) {
  __shared__ float sf[512];
  __shared__ float sb[512];
  const int tid = threadIdx.x;
  int bid = blockIdx.x;
  int b = bid / 2304, yx = bid - b * 2304;
  int y = yx / 48, x = yx - y * 48;
  for (int i = tid; i < 512; i += TPB) {
    float vf = -INFINITY, vb = -INFINITY;
    if (i < 289) {
      int dy = i / 17, dx = i - dy * 17;
      int sy = y + dy - 8, sx = x + dx - 8;
      float pv = 0.f;
      if (sy >= 0 && sy < 48 && sx >= 0 && sx < 48) pv = lm[(size_t)b * 2304 + sy * 48 + sx];
      float v = klp[((size_t)b * 289 + i) * 2304 + yx];
      vf = v * pv;
      vb = v * (1.0f - pv);
    }
    sf[i] = vf;
    sb[i] = vb;
  }
  for (int k = 2; k <= 512; k <<= 1) {
    for (int j = k >> 1; j > 0; j >>= 1) {
      __syncthreads();
      for (int t = tid; t < 512; t += TPB) {
        int ixj = t ^ j;
        if (ixj > t) {
          bool up = ((t & k) == 0);
          float a = sf[t], c = sf[ixj];
          if (up ? (a > c) : (a < c)) { sf[t] = c; sf[ixj] = a; }
          a = sb[t];
          c = sb[ixj];
          if (up ? (a > c) : (a < c)) { sb[t] = c; sb[ixj] = a; }
        }
      }
    }
  }
  __syncthreads();
  xcat[((size_t)b * 1281 + 768 + tid) * 2304 + yx] = sf[511 - tid];
  xcat[((size_t)b * 1281 + 1024 + tid) * 2304 + yx] = sb[511 - tid];
}

__global__ __launch_bounds__(TPB) void copy_p3_kernel(const float* __restrict__ p3,
                                                      float* __restrict__ xcat) {
  int idx = blockIdx.x * TPB + threadIdx.x;
  const int per_b = 256 * 2304;
  if (idx >= 2 * per_b) return;
  int b = idx / per_b, r = idx - b * per_b;
  xcat[(size_t)b * 1281 * 2304 + r] = p3[idx];
}

__global__ __launch_bounds__(TPB) void copy_pm_kernel(const float* __restrict__ lm,
                                                      float* __restrict__ xcat) {
  int idx = blockIdx.x * TPB + threadIdx.x;
  if (idx >= 2 * 2304) return;
  int b = idx / 2304, yx = idx - b * 2304;
  xcat[((size_t)b * 1281 + 1280) * 2304 + yx] = lm[idx];
}

// ===== weight preconvert: OIHW fp32 -> Wb[co][kykx][cipad] split bf16 (hi, lo) =====
__global__ __launch_bounds__(TPB) void wconv_kernel(const float* __restrict__ w,
                                                    unsigned short* __restrict__ whi,
                                                    unsigned short* __restrict__ wlo,
                                                    int Cin, int cipad, int total) {
  int i = blockIdx.x * TPB + threadIdx.x;
  if (i >= total) return;
  int ci = i % cipad;
  int rest = i / cipad;
  int kk = rest % 9;
  int co = rest / 9;
  float v = 0.f;
  if (ci < Cin) v = w[((size_t)co * Cin + ci) * 9 + kk];
  unsigned short h = f2bf(v);
  whi[i] = h;
  wlo[i] = f2bf(v - bf2f(h));
}

// ===== MFMA implicit-GEMM 3x3 conv, split-bf16 (3-term) fp32 accumulate =====
__global__ __launch_bounds__(TPB) void conv_mfma_kernel(
    const float* __restrict__ in, const unsigned short* __restrict__ whi,
    const unsigned short* __restrict__ wlo, const float* __restrict__ bias,
    float* __restrict__ outp, float* __restrict__ partial,
    int Cin, int cipad, int Cout, int H, int W, int S, int ci_per_s) {
  __shared__ uint2 sbh[900];
  __shared__ uint2 sbl[900];
  const int tid = threadIdx.x;
  const int lane = tid & 63, wid = tid >> 6;
  const int lo16 = lane & 15, hi4 = lane >> 4;
  const int wco = wid & 1, wpx = wid >> 1;
  const int tilesX = W >> 3;
  const int tx0 = (blockIdx.x % tilesX) << 3;
  const int ty0 = (blockIdx.x / tilesX) << 3;
  const int s = blockIdx.y % S;
  const int co0 = (blockIdx.y / S) * 64;
  const int b = blockIdx.z;
  const size_t HW = (size_t)H * W;
  const float* inb = in + (size_t)b * Cin * HW;
  int ci_begin = s * ci_per_s;
  int ci_end = ci_begin + ci_per_s;
  if (ci_end > cipad) ci_end = cipad;
  f4 acc[2][2];
#pragma unroll
  for (int m = 0; m < 2; ++m)
#pragma unroll
    for (int n = 0; n < 2; ++n) acc[m][n] = (f4){0.f, 0.f, 0.f, 0.f};
  const int trow0 = wpx * 4 + (lo16 >> 3);
  const int tcol0 = lo16 & 7;

  for (int ci0 = ci_begin; ci0 < ci_end; ci0 += 32) {
    __syncthreads();
    for (int u = tid; u < 1600; u += TPB) {
      int c2 = u / 100;
      int pix = u - c2 * 100;
      int prow = pix / 10;
      int pcol = pix - prow * 10;
      int gy = ty0 - 1 + prow, gx = tx0 - 1 + pcol;
      int ci = ci0 + c2 * 2;
      float v0 = 0.f, v1 = 0.f;
      if (gy >= 0 && gy < H && gx >= 0 && gx < W) {
        const float* q = inb + (size_t)ci * HW + (size_t)gy * W + gx;
        if (ci < Cin) v0 = q[0];
        if (ci + 1 < Cin) v1 = q[HW];
      }
      unsigned short h0 = f2bf(v0), h1 = f2bf(v1);
      unsigned int ph = (unsigned int)h0 | ((unsigned int)h1 << 16);
      unsigned int pl = (unsigned int)f2bf(v0 - bf2f(h0)) |
                        ((unsigned int)f2bf(v1 - bf2f(h1)) << 16);
      ((unsigned int*)sbh)[pix * 18 + c2] = ph;
      ((unsigned int*)sbl)[pix * 18 + c2] = pl;
    }
    __syncthreads();
#pragma unroll
    for (int ky = 0; ky < 3; ++ky) {
#pragma unroll
      for (int kx = 0; kx < 3; ++kx) {
        bh8 bh[2], bl[2];
#pragma unroll
        for (int n = 0; n < 2; ++n) {
          int pix = (trow0 + n * 2 + ky) * 10 + tcol0 + kx;
          int pq = pix * 9 + 2 * hi4;
          union { uint2 q[2]; bh8 v; } ub;
          ub.q[0] = sbh[pq];
          ub.q[1] = sbh[pq + 1];
          bh[n] = ub.v;
          union { uint2 q[2]; bh8 v; } ul;
          ul.q[0] = sbl[pq];
          ul.q[1] = sbl[pq + 1];
          bl[n] = ul.v;
        }
        int kykx = ky * 3 + kx;
#pragma unroll
        for (int m = 0; m < 2; ++m) {
          size_t woff = ((size_t)(co0 + wco * 32 + m * 16 + lo16) * 9 + kykx) * cipad +
                        ci0 + 8 * hi4;
          bh8 ah = *(const bh8*)(whi + woff);
          bh8 al = *(const bh8*)(wlo + woff);
#pragma unroll
          for (int n = 0; n < 2; ++n) {
            acc[m][n] = __builtin_amdgcn_mfma_f32_16x16x32_bf16(ah, bh[n], acc[m][n], 0, 0, 0);
            acc[m][n] = __builtin_amdgcn_mfma_f32_16x16x32_bf16(ah, bl[n], acc[m][n], 0, 0, 0);
            acc[m][n] = __builtin_amdgcn_mfma_f32_16x16x32_bf16(al, bh[n], acc[m][n], 0, 0, 0);
          }
        }
      }
    }
  }

#pragma unroll
  for (int m = 0; m < 2; ++m) {
    int co_r0 = co0 + wco * 32 + m * 16 + hi4 * 4;
#pragma unroll
    for (int n = 0; n < 2; ++n) {
      int py = ty0 + wpx * 4 + n * 2 + (lo16 >> 3);
      int px = tx0 + tcol0;
#pragma unroll
      for (int r = 0; r < 4; ++r) {
        int co_r = co_r0 + r;
        float v = acc[m][n][r];
        if (S == 1) {
          v += bias[co_r];
          outp[(size_t)(b * Cout + co_r) * HW + (size_t)py * W + px] = v;
        } else {
          partial[((size_t)(s * 2 + b) * Cout + co_r) * HW + (size_t)py * W + px] = v;
        }
      }
    }
  }
}

// ===== split-K reduce + bias =====
__global__ __launch_bounds__(TPB) void reduce_bias_kernel(const float* __restrict__ partial,
                                                          const float* __restrict__ bias,
                                                          float* __restrict__ outp, int S,
                                                          int Cout, int HW, int total4) {
  int i = blockIdx.x * TPB + threadIdx.x;
  if (i >= total4) return;
  int e = i * 4;
  int chw = Cout * HW;
  int b = e / chw;
  int rem = e - b * chw;
  int co = rem / HW;
  float4 acc = {0.f, 0.f, 0.f, 0.f};
  for (int ss = 0; ss < S; ++ss) {
    const float4 t = *(const float4*)(partial + (size_t)(ss * 2 + b) * chw + rem);
    acc.x += t.x; acc.y += t.y; acc.z += t.z; acc.w += t.w;
  }
  float bv = bias[co];
  float4 o = {acc.x + bv, acc.y + bv, acc.z + bv, acc.w + bv};
  *(float4*)(outp + (size_t)b * chw + rem) = o;
}

// ===== fp32 direct 3x3 conv (pred head 64->1 + sigmoid) =====
template <int CO, int ACT>
__global__ __launch_bounds__(TPB) void conv3x3_kernel(
    const float* __restrict__ in, const float* __restrict__ w,
    const float* __restrict__ bias, float* __restrict__ out,
    int Cin, int Cout, int H, int W) {
  const int CIC = 4;
  __shared__ float sin_t[CIC][18 * 50];
  int tid = threadIdx.x;
  int tx = tid & 15, ty = tid >> 4;
  int tilesX = W / 48;
  int bx = blockIdx.x % tilesX, by = blockIdx.x / tilesX;
  int co0 = blockIdx.y * CO;
  int b = blockIdx.z;
  int oy = by * 16 + ty;
  int ox = bx * 48 + tx * 3;
  float acc[CO][3];
#pragma unroll
  for (int c = 0; c < CO; ++c) { acc[c][0] = acc[c][1] = acc[c][2] = 0.f; }
  int gy0 = by * 16 - 1, gx0 = bx * 48 - 1;
  const size_t in_b = (size_t)b * Cin * H * W;
  for (int ci0 = 0; ci0 < Cin; ci0 += CIC) {
    __syncthreads();
    for (int idx = tid; idx < CIC * 900; idx += TPB) {
      int ci = idx / 900, r = idx - ci * 900;
      int row = r / 50, col = r - row * 50;
      int gy = gy0 + row, gx = gx0 + col;
      int cig = ci0 + ci;
      float v = 0.f;
      if (cig < Cin && gy >= 0 && gy < H && gx >= 0 && gx < W)
        v = in[in_b + ((size_t)cig * H + gy) * W + gx];
      sin_t[ci][r] = v;
    }
    __syncthreads();
#pragma unroll
    for (int ci = 0; ci < CIC; ++ci) {
      int cig = ci0 + ci;
      if (cig < Cin) {
        float rin[3][5];
        const float* sp = &sin_t[ci][ty * 50 + tx * 3];
#pragma unroll
        for (int d = 0; d < 5; ++d) {
          rin[0][d] = sp[d];
          rin[1][d] = sp[50 + d];
          rin[2][d] = sp[100 + d];
        }
#pragma unroll
        for (int c = 0; c < CO; ++c) {
          const float* wp = w + ((size_t)(co0 + c) * Cin + cig) * 9;
#pragma unroll
          for (int ky = 0; ky < 3; ++ky) {
#pragma unroll
            for (int kx = 0; kx < 3; ++kx) {
              float wv = wp[ky * 3 + kx];
              acc[c][0] = fmaf(wv, rin[ky][kx], acc[c][0]);
              acc[c][1] = fmaf(wv, rin[ky][kx + 1], acc[c][1]);
              acc[c][2] = fmaf(wv, rin[ky][kx + 2], acc[c][2]);
            }
          }
        }
      }
    }
  }
#pragma unroll
  for (int c = 0; c < CO; ++c) {
    float bv = bias[co0 + c];
    size_t o = (((size_t)b * Cout + co0 + c) * H + oy) * W + ox;
#pragma unroll
    for (int pimg = 0; pimg < 3; ++pimg) {
      float v = acc[c][pimg] + bv;
      if (ACT == 2) v = 1.0f / (1.0f + expf(-v));
      out[o + pimg] = v;
    }
  }
}

// ===== InstanceNorm (biased var, eps 1e-5) + ReLU, in place; block per (b,c) =====
__global__ __launch_bounds__(TPB) void inorm_relu_kernel(float* __restrict__ x, int N, int relu) {
  __shared__ float red[4];
  float* p = x + (size_t)blockIdx.x * N;
  int tid = threadIdx.x;
  float s = 0.f;
  for (int i = tid; i < N; i += TPB) s += p[i];
  s = wave_sum64(s);
  if ((tid & 63) == 0) red[tid >> 6] = s;
  __syncthreads();
  float mean = (red[0] + red[1] + red[2] + red[3]) / (float)N;
  __syncthreads();
  float v = 0.f;
  for (int i = tid; i < N; i += TPB) {
    float d = p[i] - mean;
    v = fmaf(d, d, v);
  }
  v = wave_sum64(v);
  if ((tid & 63) == 0) red[tid >> 6] = v;
  __syncthreads();
  float var = (red[0] + red[1] + red[2] + red[3]) / (float)N;
  float inv = 1.0f / sqrtf(var + 1e-5f);
  for (int i = tid; i < N; i += TPB) {
    float t = (p[i] - mean) * inv;
    if (relu) t = fmaxf(t, 0.f);
    p[i] = t;
  }
}

__global__ __launch_bounds__(TPB) void resize_ac_kernel(const float* __restrict__ in,
                                                        float* __restrict__ out, int BC,
                                                        int h, int w, int H, int W,
                                                        float ry, float rx) {
  int total = BC * H * W;
  for (int idx = blockIdx.x * TPB + threadIdx.x; idx < total; idx += gridDim.x * TPB) {
    int bc = idx / (H * W), r = idx - bc * (H * W);
    int Y = r / W, X = r - Y * W;
    float ys = Y * ry, xs = X * rx;
    int y0 = (int)floorf(ys);
    y0 = y0 < 0 ? 0 : (y0 > h - 1 ? h - 1 : y0);
    int x0 = (int)floorf(xs);
    x0 = x0 < 0 ? 0 : (x0 > w - 1 ? w - 1 : x0);
    int y1 = y0 + 1 < h ? y0 + 1 : h - 1;
    int x1 = x0 + 1 < w ? x0 + 1 : w - 1;
    float wy = ys - (float)y0, wx = xs - (float)x0;
    const float* ip = in + (size_t)bc * h * w;
    float a = ip[(size_t)y0 * w + x0], b2 = ip[(size_t)y0 * w + x1];
    float c = ip[(size_t)y1 * w + x0], d = ip[(size_t)y1 * w + x1];
    float top = a * (1.f - wy) + c * wy;
    float bot = b2 * (1.f - wy) + d * wy;
    out[idx] = top * (1.f - wx) + bot * wx;
  }
}

__global__ __launch_bounds__(TPB) void add_kernel(float* __restrict__ dst,
                                                  const float* __restrict__ src, int n) {
  int i = blockIdx.x * TPB + threadIdx.x;
  if (i < n) dst[i] += src[i];
}

extern "C" void kernel_launch(void* const* d_in, const int* in_sizes, int n_in,
                              void* d_out, int out_size, void* d_ws, size_t ws_size,
                              hipStream_t stream) {
  (void)in_sizes; (void)n_in; (void)out_size;
  const float* p3 = (const float*)d_in[0];
  const float* p2 = (const float*)d_in[1];
  const float* p1 = (const float*)d_in[2];
  const float* kg1 = (const float*)d_in[3];
  const float* klp = (const float*)d_in[4];
  const float* key_mask = (const float*)d_in[5];
  const float* pre_mask = (const float*)d_in[6];
  const float* conv_top_w = (const float*)d_in[7];
  const float* conv_top_b = (const float*)d_in[8];
  const float* aic_top_w1 = (const float*)d_in[9];
  const float* aic_top_b1 = (const float*)d_in[10];
  const float* aic_top_w2 = (const float*)d_in[11];
  const float* aic_top_b2 = (const float*)d_in[12];
  const float* r1a_w1 = (const float*)d_in[13];
  const float* r1a_b1 = (const float*)d_in[14];
  const float* r1a_w2 = (const float*)d_in[15];
  const float* r1a_b2 = (const float*)d_in[16];
  const float* r1b_w1 = (const float*)d_in[17];
  const float* r1b_b1 = (const float*)d_in[18];
  const float* r1b_w2 = (const float*)d_in[19];
  const float* r1b_b2 = (const float*)d_in[20];
  const float* r2a_w1 = (const float*)d_in[21];
  const float* r2a_b1 = (const float*)d_in[22];
  const float* r2a_w2 = (const float*)d_in[23];
  const float* r2a_b2 = (const float*)d_in[24];
  const float* r2b_w1 = (const float*)d_in[25];
  const float* r2b_b1 = (const float*)d_in[26];
  const float* r2b_w2 = (const float*)d_in[27];
  const float* r2b_b2 = (const float*)d_in[28];
  const float* dec_w = (const float*)d_in[29];
  const float* dec_b = (const float*)d_in[30];
  const float* pred_w = (const float*)d_in[31];
  const float* pred_b = (const float*)d_in[32];
  float* outp = (float*)d_out;

  // workspace layout (float units)
  const size_t OFF_GM = 0;
  const size_t OFF_LM = 4608;
  const size_t OFF_XCAT = 9216;
  const size_t OFF_A0 = 5912064;
  const size_t OFF_A1 = 7091712;
  const size_t OFF_H48 = 8271360;
  const size_t OFF_YB = 8566272;
  const size_t OFF_H96 = 13284864;
  const size_t OFF_D96 = 14464512;
  const size_t OFF_P = 15644160;
  const size_t OFF_WB = 20362752;
  const size_t TOTAL_F = 23385600;
  if (ws_size < TOTAL_F * sizeof(float)) return;

  float* ws = (float*)d_ws;
  float* gm = ws + OFF_GM;
  float* lm = ws + OFF_LM;
  float* xcat = ws + OFF_XCAT;
  float* a0 = ws + OFF_A0;
  float* a1 = ws + OFF_A1;
  float* h48 = ws + OFF_H48;
  float* yB = ws + OFF_YB;
  float* h96 = ws + OFF_H96;
  float* d96 = ws + OFF_D96;
  float* Pbuf = ws + OFF_P;
  unsigned short* wbh = (unsigned short*)(ws + OFF_WB);
  const size_t WHALF = 3022848;
  unsigned short* wbl = wbh + WHALF;
  float* yA = xcat;
  float* zA = yB;
  float* zH = xcat;

  pool8_kernel<<<(2 * 2304 + TPB - 1) / TPB, TPB, 0, stream>>>(key_mask, gm, 2 * 2304);
  pool8_kernel<<<(2 * 2304 + TPB - 1) / TPB, TPB, 0, stream>>>(pre_mask, lm, 2 * 2304);
  topk_global_kernel<<<2 * 2304, TPB, 0, stream>>>(kg1, gm, xcat);
  topk_local_kernel<<<2 * 2304, TPB, 0, stream>>>(klp, lm, xcat);
  copy_p3_kernel<<<(2 * 256 * 2304 + TPB - 1) / TPB, TPB, 0, stream>>>(p3, xcat);
  copy_pm_kernel<<<(2 * 2304 + TPB - 1) / TPB, TPB, 0, stream>>>(lm, xcat);

  auto run_conv = [&](const float* src, const float* w, const float* bb, float* dst,
                      int Cin, int Cout, int H, int W, int S) {
    int cipad = (Cin + 31) & ~31;
    int wtotal = Cout * 9 * cipad;
    wconv_kernel<<<(wtotal + TPB - 1) / TPB, TPB, 0, stream>>>(w, wbh, wbl, Cin, cipad, wtotal);
    int chunks = cipad / 32;
    int cps = ((chunks + S - 1) / S) * 32;
    dim3 grid((W / 8) * (H / 8), (Cout / 64) * S, 2);
    conv_mfma_kernel<<<grid, TPB, 0, stream>>>(src, wbh, wbl, bb, dst, Pbuf, Cin, cipad,
                                               Cout, H, W, S, cps);
    if (S > 1) {
      int HW = H * W;
      int total4 = 2 * Cout * HW / 4;
      reduce_bias_kernel<<<(total4 + TPB - 1) / TPB, TPB, 0, stream>>>(Pbuf, bb, dst, S,
                                                                       Cout, HW, total4);
    }
  };
  auto inorm = [&](float* x, int C, int N) {
    inorm_relu_kernel<<<2 * C, TPB, 0, stream>>>(x, N, 1);
  };

  // top fuse @48
  run_conv(xcat, conv_top_w, conv_top_b, a0, 1281, 256, 48, 48, 4);
  run_conv(a0, aic_top_w1, aic_top_b1, h48, 256, 64, 48, 48, 8);
  inorm(h48, 64, 2304);
  run_conv(h48, aic_top_w2, aic_top_b2, a1, 64, 256, 48, 48, 2);
  inorm(a1, 256, 2304);

  // 48 -> 96
  {
    float ry = (float)((48.0 - 1.0) / (96.0 - 1.0));
    int total = 2 * 256 * 96 * 96;
    resize_ac_kernel<<<(total + TPB - 1) / TPB, TPB, 0, stream>>>(a1, yA, 2 * 256, 48, 48,
                                                                  96, 96, ry, ry);
  }
  run_conv(yA, r1a_w1, r1a_b1, h96, 256, 64, 96, 96, 4);
  inorm(h96, 64, 9216);
  run_conv(h96, r1a_w2, r1a_b2, yB, 64, 256, 96, 96, 1);
  inorm(yB, 256, 9216);
  add_kernel<<<(2 * 256 * 9216 + TPB - 1) / TPB, TPB, 0, stream>>>(yB, p2, 2 * 256 * 9216);
  run_conv(yB, r1b_w1, r1b_b1, h96, 256, 64, 96, 96, 4);
  inorm(h96, 64, 9216);
  run_conv(h96, r1b_w2, r1b_b2, yA, 64, 256, 96, 96, 1);
  inorm(yA, 256, 9216);
  run_conv(yA, dec_w, dec_b, d96, 256, 64, 96, 96, 4);

  // 96 -> 192
  {
    float ry = (float)((96.0 - 1.0) / (192.0 - 1.0));
    int total = 2 * 64 * 192 * 192;
    resize_ac_kernel<<<(total + TPB - 1) / TPB, TPB, 0, stream>>>(d96, zA, 2 * 64, 96, 96,
                                                                  192, 192, ry, ry);
  }
  run_conv(zA, r2a_w1, r2a_b1, zH, 64, 64, 192, 192, 1);
  inorm(zH, 64, 36864);
  run_conv(zH, r2a_w2, r2a_b2, zA, 64, 64, 192, 192, 1);
  inorm(zA, 64, 36864);
  add_kernel<<<(2 * 64 * 36864 + TPB - 1) / TPB, TPB, 0, stream>>>(zA, p1, 2 * 64 * 36864);
  run_conv(zA, r2b_w1, r2b_b1, zH, 64, 64, 192, 192, 1);
  inorm(zH, 64, 36864);
  run_conv(zH, r2b_w2, r2b_b2, zA, 64, 64, 192, 192, 1);
  inorm(zA, 64, 36864);

  // pred head: 64 -> 1 + sigmoid -> d_out
  {
    dim3 grid((192 / 48) * (192 / 16), 1, 2);
    conv3x3_kernel<1, 2><<<grid, TPB, 0, stream>>>(zA, pred_w, pred_b, outp, 64, 1, 192, 192);
  }
}

// Round 5
// 1463.235 us; speedup vs baseline: 5.1128x; 1.1944x over previous
//
#include <hip/hip_runtime.h>
#include <math.h>

#define TPB 256

typedef short bh8 __attribute__((ext_vector_type(8)));
typedef float f4 __attribute__((ext_vector_type(4)));
typedef unsigned short ushort_t;

__device__ __forceinline__ unsigned short f2bf(float x) {
  unsigned int u = __float_as_uint(x);
  unsigned int r = (u + 0x7fffu + ((u >> 16) & 1u)) >> 16;
  return (unsigned short)r;
}
__device__ __forceinline__ float bf2f(unsigned short h) {
  return __uint_as_float(((unsigned int)h) << 16);
}
__device__ __forceinline__ unsigned key_of(float x) {
  unsigned u = __float_as_uint(x);
  return u ^ ((u >> 31) ? 0xFFFFFFFFu : 0x80000000u);
}
__device__ __forceinline__ float un_key(unsigned k) {
  unsigned u = k ^ ((k >> 31) ? 0x80000000u : 0xFFFFFFFFu);
  return __uint_as_float(u);
}

// ===== 8x8 max pool: [B,1,384,384] -> [B,2304] =====
__global__ __launch_bounds__(TPB) void pool8_kernel(const float* __restrict__ in,
                                                    float* __restrict__ out, int total) {
  int idx = blockIdx.x * TPB + threadIdx.x;
  if (idx >= total) return;
  int b = idx / 2304, yx = idx - b * 2304;
  int y = yx / 48, x = yx - y * 48;
  const float* p = in + ((size_t)b * 384 + (size_t)y * 8) * 384 + (size_t)x * 8;
  float m = -INFINITY;
#pragma unroll
  for (int i = 0; i < 8; ++i)
#pragma unroll
    for (int j = 0; j < 8; ++j) m = fmaxf(m, p[(size_t)i * 384 + j]);
  out[idx] = m;
}

// ===== global top-k (radix select + bitonic 256), NHWC writes, XCD-chunk swizzle =====
__global__ __launch_bounds__(TPB) void topk_global_kernel(const float* __restrict__ kg1,
                                                          const float* __restrict__ gm,
                                                          float* __restrict__ xcat) {
  __shared__ unsigned histF[256], histB[256];
  __shared__ unsigned soutF[256], soutB[256];
  __shared__ unsigned selT[2], selA[2];
  __shared__ unsigned cntG[2], cntE[2];
  const int tid = threadIdx.x;
  const int lane = tid & 63, wid = tid >> 6;
  int bid = (blockIdx.x & 7) * 576 + (blockIdx.x >> 3);  // XCD-chunked swizzle (4608=8*576)
  int b = bid / 2304, yx = bid - b * 2304;
  const float* kp = kg1 + (size_t)b * 2304 * 2304 + yx;
  const float* gp = gm + (size_t)b * 2304;
  unsigned kF[9], kB[9];
#pragma unroll
  for (int j = 0; j < 9; ++j) {
    int i = tid + 256 * j;
    float v = kp[(size_t)i * 2304];
    float g = gp[i];
    kF[j] = key_of(v * g);
    kB[j] = key_of(v * (1.0f - g));
  }
  unsigned prefF = 0, prefB = 0;
  unsigned KF = 256, KB = 256;
  unsigned gtF = 0, gtB = 0;
#pragma unroll
  for (int p = 0; p < 4; ++p) {
    const int shift = 24 - 8 * p;
    histF[tid] = 0;
    histB[tid] = 0;
    __syncthreads();
#pragma unroll
    for (int j = 0; j < 9; ++j) {
      if (p == 0 || (kF[j] >> (shift + 8)) == prefF)
        atomicAdd(&histF[(kF[j] >> shift) & 0xFFu], 1u);
      if (p == 0 || (kB[j] >> (shift + 8)) == prefB)
        atomicAdd(&histB[(kB[j] >> shift) & 0xFFu], 1u);
    }
    __syncthreads();
    if (wid < 2) {
      unsigned* h = wid ? histB : histF;
      unsigned K = wid ? KB : KF;
      unsigned h0 = h[4 * lane], h1 = h[4 * lane + 1];
      unsigned h2 = h[4 * lane + 2], h3 = h[4 * lane + 3];
      unsigned x = h0 + h1 + h2 + h3;
#pragma unroll
      for (int d = 1; d < 64; d <<= 1) {
        unsigned y = __shfl_down(x, d, 64);
        if (lane + d < 64) x += y;
      }
      unsigned long long m = __ballot(x >= K);
      int tl = 63 - __clzll(m);
      if (lane == tl) {
        unsigned s1 = x - h0, s2 = s1 - h1, s3 = s2 - h2, s4 = s3 - h3;
        int jj;
        unsigned A;
        if (s3 >= K) { jj = 3; A = s4; }
        else if (s2 >= K) { jj = 2; A = s3; }
        else if (s1 >= K) { jj = 1; A = s2; }
        else { jj = 0; A = s1; }
        selT[wid] = 4 * tl + jj;
        selA[wid] = A;
      }
    }
    __syncthreads();
    unsigned TF = selT[0], AF = selA[0];
    unsigned TB = selT[1], AB = selA[1];
    prefF = (prefF << 8) | TF; gtF += AF; KF -= AF;
    prefB = (prefB << 8) | TB; gtB += AB; KB -= AB;
    __syncthreads();
  }
  const unsigned tF = prefF, tB = prefB;
  const unsigned nGTF = gtF, needF = KF;
  const unsigned nGTB = gtB, needB = KB;
  if (tid == 0) { cntG[0] = 0; cntG[1] = 0; cntE[0] = 0; cntE[1] = 0; }
  __syncthreads();
#pragma unroll
  for (int j = 0; j < 9; ++j) {
    unsigned k = kF[j];
    if (k > tF) soutF[atomicAdd(&cntG[0], 1u)] = k;
    else if (k == tF) {
      unsigned e = atomicAdd(&cntE[0], 1u);
      if (e < needF) soutF[nGTF + e] = tF;
    }
    k = kB[j];
    if (k > tB) soutB[atomicAdd(&cntG[1], 1u)] = k;
    else if (k == tB) {
      unsigned e = atomicAdd(&cntE[1], 1u);
      if (e < needB) soutB[nGTB + e] = tB;
    }
  }
  __syncthreads();
  for (int kk = 2; kk <= 256; kk <<= 1) {
    for (int j = kk >> 1; j > 0; j >>= 1) {
      int t = tid, ixj = t ^ j;
      if (ixj > t) {
        bool up = ((t & kk) == 0);
        unsigned a = soutF[t], c = soutF[ixj];
        if (up ? (a > c) : (a < c)) { soutF[t] = c; soutF[ixj] = a; }
        a = soutB[t]; c = soutB[ixj];
        if (up ? (a > c) : (a < c)) { soutB[t] = c; soutB[ixj] = a; }
      }
      __syncthreads();
    }
  }
  size_t base = ((size_t)(b * 2304 + yx)) * 1312;
  xcat[base + 256 + tid] = un_key(soutF[255 - tid]);
  xcat[base + 512 + tid] = un_key(soutB[255 - tid]);
}

// ===== local top-k (fused bitonic over 512), NHWC writes =====
__global__ __launch_bounds__(TPB) void topk_local_kernel(const float* __restrict__ klp,
                                                         const float* __restrict__ lm,
                                                         float* __restrict__ xcat) {
  __shared__ float sf[512];
  __shared__ float sb[512];
  const int tid = threadIdx.x;
  int bid = (blockIdx.x & 7) * 576 + (blockIdx.x >> 3);
  int b = bid / 2304, yx = bid - b * 2304;
  int y = yx / 48, x = yx - y * 48;
  for (int i = tid; i < 512; i += TPB) {
    float vf = -INFINITY, vb = -INFINITY;
    if (i < 289) {
      int dy = i / 17, dx = i - dy * 17;
      int sy = y + dy - 8, sx = x + dx - 8;
      float pv = 0.f;
      if (sy >= 0 && sy < 48 && sx >= 0 && sx < 48) pv = lm[(size_t)b * 2304 + sy * 48 + sx];
      float v = klp[((size_t)b * 289 + i) * 2304 + yx];
      vf = v * pv;
      vb = v * (1.0f - pv);
    }
    sf[i] = vf;
    sb[i] = vb;
  }
  for (int k = 2; k <= 512; k <<= 1) {
    for (int j = k >> 1; j > 0; j >>= 1) {
      __syncthreads();
      for (int t = tid; t < 512; t += TPB) {
        int ixj = t ^ j;
        if (ixj > t) {
          bool up = ((t & k) == 0);
          float a = sf[t], c = sf[ixj];
          if (up ? (a > c) : (a < c)) { sf[t] = c; sf[ixj] = a; }
          a = sb[t]; c = sb[ixj];
          if (up ? (a > c) : (a < c)) { sb[t] = c; sb[ixj] = a; }
        }
      }
    }
  }
  __syncthreads();
  size_t base = ((size_t)(b * 2304 + yx)) * 1312;
  xcat[base + 768 + tid] = sf[511 - tid];
  xcat[base + 1024 + tid] = sb[511 - tid];
}

// ===== NCHW fp32 -> NHWC fp32 transpose (64c x 64px LDS tiles) =====
__global__ __launch_bounds__(TPB) void tposef_kernel(const float* __restrict__ src,
                                                     float* __restrict__ dst, int C, int HW,
                                                     int DS) {
  __shared__ float tile[64][65];
  int px0 = blockIdx.x * 64;
  int c0 = blockIdx.y * 64;
  int b = blockIdx.z;
  int tid = threadIdx.x;
#pragma unroll
  for (int i = 0; i < 16; ++i) {
    int c = (tid >> 6) + i * 4, p = tid & 63;
    tile[c][p] = src[((size_t)b * C + c0 + c) * HW + px0 + p];
  }
  __syncthreads();
#pragma unroll
  for (int i = 0; i < 16; ++i) {
    int c = tid & 63, p = (tid >> 6) + i * 4;
    dst[((size_t)b * HW + px0 + p) * DS + c0 + c] = tile[c][p];
  }
}

// ===== NCHW fp32 -> NHWC bf16 transpose =====
__global__ __launch_bounds__(TPB) void tposeh_kernel(const float* __restrict__ src,
                                                     ushort_t* __restrict__ dst, int C, int HW,
                                                     int DS) {
  __shared__ float tile[64][65];
  int px0 = blockIdx.x * 64;
  int c0 = blockIdx.y * 64;
  int b = blockIdx.z;
  int tid = threadIdx.x;
#pragma unroll
  for (int i = 0; i < 16; ++i) {
    int c = (tid >> 6) + i * 4, p = tid & 63;
    tile[c][p] = src[((size_t)b * C + c0 + c) * HW + px0 + p];
  }
  __syncthreads();
#pragma unroll
  for (int i = 0; i < 16; ++i) {
    int c = tid & 63, p = (tid >> 6) + i * 4;
    dst[((size_t)b * HW + px0 + p) * DS + c0 + c] = f2bf(tile[c][p]);
  }
}

// ===== pm channel + zero pad channels of xcat =====
__global__ __launch_bounds__(TPB) void pm_pad_kernel(const float* __restrict__ lm,
                                                     float* __restrict__ xcat) {
  int idx = blockIdx.x * TPB + threadIdx.x;
  if (idx >= 2 * 2304 * 32) return;
  int ch = idx & 31;
  int r = idx >> 5;  // b*2304+yx
  xcat[(size_t)r * 1312 + 1280 + ch] = (ch == 0) ? lm[r] : 0.f;
}

// ===== weight preconvert: OIHW fp32 -> [co][kykx][CIP] split bf16; co/ci zero-padded =====
__global__ __launch_bounds__(TPB) void wconv_kernel(const float* __restrict__ w,
                                                    ushort_t* __restrict__ whi,
                                                    ushort_t* __restrict__ wlo,
                                                    int CinW, int CIP, int CoutReal,
                                                    int total) {
  int i = blockIdx.x * TPB + threadIdx.x;
  if (i >= total) return;
  int ci = i % CIP;
  int rest = i / CIP;
  int kk = rest % 9;
  int co = rest / 9;
  float v = 0.f;
  if (ci < CinW && co < CoutReal) v = w[((size_t)co * CinW + ci) * 9 + kk];
  unsigned short h = f2bf(v);
  whi[i] = h;
  wlo[i] = f2bf(v - bf2f(h));
}

// ===== MFMA implicit-GEMM 3x3 conv, NHWC, split-bf16 3-term =====
// tile: MB co x 128 px (16 rows x 8 cols); halo 18x10 staged per 32-ci chunk in LDS.
// MFR = MB/32 (2 or 4). ACT: 0 = bias+store NHWC (or partial), 1 = pred sigmoid, co0 only.
template <int MFR, int ACT>
__global__ __launch_bounds__(TPB) void conv_mfma_kernel(
    const float* __restrict__ in, const ushort_t* __restrict__ whi,
    const ushort_t* __restrict__ wlo, const float* __restrict__ bias,
    float* __restrict__ outp, float* __restrict__ partial,
    int CIP, int Cout, int H, int W, int S, int ci_per_s) {
  __shared__ unsigned sH[3600];  // [180 px][20 words] bf16-hi (16 used)
  __shared__ unsigned sL[3600];
  const int MB = MFR * 32;
  const int tid = threadIdx.x;
  const int lane = tid & 63, wid = tid >> 6;
  const int lo16 = lane & 15, hi4 = lane >> 4;
  const int wco = wid & 1, wpx = wid >> 1;
  const int tilesX = W >> 3;
  const int tx0 = (blockIdx.x % tilesX) << 3;
  const int ty0 = (blockIdx.x / tilesX) << 4;
  const int s = blockIdx.y % S;
  const int co0 = (blockIdx.y / S) * MB;
  const int b = blockIdx.z;
  const size_t HW = (size_t)H * W;
  const float* inb = in + (size_t)b * HW * CIP;
  int ci_begin = s * ci_per_s;
  int ci_end = ci_begin + ci_per_s;
  if (ci_end > CIP) ci_end = CIP;
  f4 acc[MFR][4];
#pragma unroll
  for (int m = 0; m < MFR; ++m)
#pragma unroll
    for (int n = 0; n < 4; ++n) acc[m][n] = (f4){0.f, 0.f, 0.f, 0.f};

  for (int ci0 = ci_begin; ci0 < ci_end; ci0 += 32) {
    __syncthreads();
    // stage 180 px x 32 ci (fp32 NHWC -> split bf16, packed 2/word)
#pragma unroll
    for (int it = 0; it < 6; ++it) {
      int u = tid + it * TPB;
      if (u < 1440) {
        int px = u >> 3, q = u & 7;
        int prow = px / 10, pcol = px - prow * 10;
        int gy = ty0 - 1 + prow, gx = tx0 - 1 + pcol;
        float4 v = {0.f, 0.f, 0.f, 0.f};
        if (gy >= 0 && gy < H && gx >= 0 && gx < W)
          v = *(const float4*)(inb + ((size_t)gy * W + gx) * CIP + ci0 + q * 4);
        unsigned short h0 = f2bf(v.x), h1 = f2bf(v.y), h2 = f2bf(v.z), h3 = f2bf(v.w);
        unsigned short l0 = f2bf(v.x - bf2f(h0)), l1 = f2bf(v.y - bf2f(h1));
        unsigned short l2 = f2bf(v.z - bf2f(h2)), l3 = f2bf(v.w - bf2f(h3));
        uint2 hw = {(unsigned)h0 | ((unsigned)h1 << 16), (unsigned)h2 | ((unsigned)h3 << 16)};
        uint2 lw = {(unsigned)l0 | ((unsigned)l1 << 16), (unsigned)l2 | ((unsigned)l3 << 16)};
        *(uint2*)&sH[px * 20 + q * 2] = hw;
        *(uint2*)&sL[px * 20 + q * 2] = lw;
      }
    }
    __syncthreads();
#pragma unroll
    for (int ky = 0; ky < 3; ++ky) {
#pragma unroll
      for (int kx = 0; kx < 3; ++kx) {
        const int kykx = ky * 3 + kx;
        bh8 bh[4], bl[4];
#pragma unroll
        for (int n = 0; n < 4; ++n) {
          int pix = (wpx * 8 + n * 2 + (lo16 >> 3) + ky) * 10 + (lo16 & 7) + kx;
          union { uint4 q; bh8 v; } ub, ul;
          ub.q = *(const uint4*)&sH[pix * 20 + 4 * hi4];
          ul.q = *(const uint4*)&sL[pix * 20 + 4 * hi4];
          bh[n] = ub.v;
          bl[n] = ul.v;
        }
#pragma unroll
        for (int m = 0; m < MFR; ++m) {
          size_t woff = ((size_t)(co0 + wco * (MB / 2) + m * 16 + lo16) * 9 + kykx) * CIP +
                        ci0 + 8 * hi4;
          bh8 ah = *(const bh8*)(whi + woff);
          bh8 al = *(const bh8*)(wlo + woff);
#pragma unroll
          for (int n = 0; n < 4; ++n) {
            acc[m][n] = __builtin_amdgcn_mfma_f32_16x16x32_bf16(ah, bh[n], acc[m][n], 0, 0, 0);
            acc[m][n] = __builtin_amdgcn_mfma_f32_16x16x32_bf16(ah, bl[n], acc[m][n], 0, 0, 0);
            acc[m][n] = __builtin_amdgcn_mfma_f32_16x16x32_bf16(al, bh[n], acc[m][n], 0, 0, 0);
          }
        }
      }
    }
  }

#pragma unroll
  for (int m = 0; m < MFR; ++m) {
#pragma unroll
    for (int n = 0; n < 4; ++n) {
      int py = ty0 + wpx * 8 + n * 2 + (lo16 >> 3);
      int pxx = tx0 + (lo16 & 7);
      int co_r0 = co0 + wco * (MB / 2) + m * 16 + hi4 * 4;
      if (ACT == 1) {
        if (wco == 0 && m == 0 && hi4 == 0) {
          float v = acc[0][n][0] + bias[0];
          outp[(size_t)b * HW + (size_t)py * W + pxx] = 1.0f / (1.0f + expf(-v));
        }
      } else if (S == 1) {
        float4 bv = *(const float4*)(bias + co_r0);
        float4 o = {acc[m][n][0] + bv.x, acc[m][n][1] + bv.y, acc[m][n][2] + bv.z,
                    acc[m][n][3] + bv.w};
        *(float4*)(outp + (((size_t)b * HW + (size_t)py * W + pxx) * Cout + co_r0)) = o;
      } else {
        float4 o = {acc[m][n][0], acc[m][n][1], acc[m][n][2], acc[m][n][3]};
        *(float4*)(partial + (((size_t)(s * 2 + b) * HW + (size_t)py * W + pxx) * Cout + co_r0)) = o;
      }
    }
  }
}

// ===== split-K reduce + bias (NHWC) =====
__global__ __launch_bounds__(TPB) void reduce_nhwc_kernel(const float* __restrict__ partial,
                                                          const float* __restrict__ bias,
                                                          float* __restrict__ outp, int S,
                                                          int Cout, int HW, int total4) {
  int i = blockIdx.x * TPB + threadIdx.x;
  if (i >= total4) return;
  int e = i * 4;
  int CHW = Cout * HW;
  int b = e / CHW;
  int rem = e - b * CHW;
  int co = e % Cout;
  float4 acc = {0.f, 0.f, 0.f, 0.f};
  for (int ss = 0; ss < S; ++ss) {
    const float4 t = *(const float4*)(partial + (size_t)(ss * 2 + b) * CHW + rem);
    acc.x += t.x; acc.y += t.y; acc.z += t.z; acc.w += t.w;
  }
  float4 bv = *(const float4*)(bias + co);
  float4 o = {acc.x + bv.x, acc.y + bv.y, acc.z + bv.z, acc.w + bv.w};
  *(float4*)(outp + (size_t)b * CHW + rem) = o;
}

// ===== InstanceNorm NHWC: stats (64 slices) -> finalize -> apply(+res+relu) =====
__global__ __launch_bounds__(TPB) void in_stats_kernel(const float* __restrict__ x,
                                                       float* __restrict__ stat, int N, int C) {
  __shared__ float ls[4][64], lq[4][64];
  int CG = C >> 6;
  int b = blockIdx.x / CG, cg = blockIdx.x % CG;
  int slice = blockIdx.y;
  int c = threadIdx.x & 63, p = threadIdx.x >> 6;
  int cnt = N >> 6;
  int base = slice * cnt;
  float s = 0.f, q = 0.f;
  const float* xp = x + ((size_t)b * N) * C + cg * 64 + c;
  for (int px = base + p; px < base + cnt; px += 4) {
    float v = xp[(size_t)px * C];
    s += v;
    q = fmaf(v, v, q);
  }
  ls[p][c] = s;
  lq[p][c] = q;
  __syncthreads();
  if (threadIdx.x < 64) {
    float S = ls[0][threadIdx.x] + ls[1][threadIdx.x] + ls[2][threadIdx.x] + ls[3][threadIdx.x];
    float Q = lq[0][threadIdx.x] + lq[1][threadIdx.x] + lq[2][threadIdx.x] + lq[3][threadIdx.x];
    int Ctot = 2 * C;
    int idx = b * C + cg * 64 + threadIdx.x;
    stat[(size_t)(slice * Ctot + idx) * 2] = S;
    stat[(size_t)(slice * Ctot + idx) * 2 + 1] = Q;
  }
}

__global__ __launch_bounds__(TPB) void in_final_kernel(const float* __restrict__ stat,
                                                       float* __restrict__ mean,
                                                       float* __restrict__ inv, int N, int Ctot) {
  int idx = blockIdx.x * TPB + threadIdx.x;
  if (idx >= Ctot) return;
  float S = 0.f, Q = 0.f;
  for (int sl = 0; sl < 64; ++sl) {
    S += stat[(size_t)(sl * Ctot + idx) * 2];
    Q += stat[(size_t)(sl * Ctot + idx) * 2 + 1];
  }
  float m = S / (float)N;
  float var = Q / (float)N - m * m;
  if (var < 0.f) var = 0.f;
  mean[idx] = m;
  inv[idx] = 1.0f / sqrtf(var + 1e-5f);
}

// RES: 0 none, 1 bf16 residual, 2 fp32 residual
template <int RES>
__global__ __launch_bounds__(TPB) void in_apply_kernel(float* __restrict__ x,
                                                       const float* __restrict__ mean,
                                                       const float* __restrict__ inv,
                                                       const void* __restrict__ res, int N,
                                                       int C, int total4) {
  int NC = N * C;
  for (int i = blockIdx.x * TPB + threadIdx.x; i < total4; i += gridDim.x * TPB) {
    int e = i * 4;
    int c = e % C;
    int b = e / NC;
    int midx = b * C + c;
    float4 m4 = *(const float4*)(mean + midx);
    float4 i4 = *(const float4*)(inv + midx);
    float4 v = *(float4*)(x + e);
    float4 o;
    o.x = fmaxf((v.x - m4.x) * i4.x, 0.f);
    o.y = fmaxf((v.y - m4.y) * i4.y, 0.f);
    o.z = fmaxf((v.z - m4.z) * i4.z, 0.f);
    o.w = fmaxf((v.w - m4.w) * i4.w, 0.f);
    if (RES == 1) {
      const ushort_t* r = (const ushort_t*)res + e;
      o.x += bf2f(r[0]); o.y += bf2f(r[1]); o.z += bf2f(r[2]); o.w += bf2f(r[3]);
    } else if (RES == 2) {
      const float4 r = *(const float4*)((const float*)res + e);
      o.x += r.x; o.y += r.y; o.z += r.z; o.w += r.w;
    }
    *(float4*)(x + e) = o;
  }
}

// ===== bilinear resize align_corners, NHWC, float4 over channels =====
__global__ __launch_bounds__(TPB) void resize4_kernel(const float* __restrict__ in,
                                                      float* __restrict__ out, int C, int hin,
                                                      int win, int Hout, int Wout, float r,
                                                      int total4) {
  for (int i = blockIdx.x * TPB + threadIdx.x; i < total4; i += gridDim.x * TPB) {
    int e = i * 4;
    int c = e % C;
    int t = e / C;
    int X = t % Wout;
    int t2 = t / Wout;
    int Y = t2 % Hout;
    int b = t2 / Hout;
    float ys = Y * r, xs = X * r;
    int y0 = (int)floorf(ys);
    if (y0 > hin - 1) y0 = hin - 1;
    int x0 = (int)floorf(xs);
    if (x0 > win - 1) x0 = win - 1;
    int y1 = y0 + 1 < hin ? y0 + 1 : hin - 1;
    int x1 = x0 + 1 < win ? x0 + 1 : win - 1;
    float wy = ys - (float)y0, wx = xs - (float)x0;
    const float* ip = in + ((size_t)b * hin * win) * C + c;
    float4 a = *(const float4*)(ip + ((size_t)y0 * win + x0) * C);
    float4 bb = *(const float4*)(ip + ((size_t)y0 * win + x1) * C);
    float4 cc = *(const float4*)(ip + ((size_t)y1 * win + x0) * C);
    float4 d = *(const float4*)(ip + ((size_t)y1 * win + x1) * C);
    float4 o;
    o.x = (a.x * (1.f - wy) + cc.x * wy) * (1.f - wx) + (bb.x * (1.f - wy) + d.x * wy) * wx;
    o.y = (a.y * (1.f - wy) + cc.y * wy) * (1.f - wx) + (bb.y * (1.f - wy) + d.y * wy) * wx;
    o.z = (a.z * (1.f - wy) + cc.z * wy) * (1.f - wx) + (bb.z * (1.f - wy) + d.z * wy) * wx;
    o.w = (a.w * (1.f - wy) + cc.w * wy) * (1.f - wx) + (bb.w * (1.f - wy) + d.w * wy) * wx;
    *(float4*)(out + e) = o;
  }
}

extern "C" void kernel_launch(void* const* d_in, const int* in_sizes, int n_in,
                              void* d_out, int out_size, void* d_ws, size_t ws_size,
                              hipStream_t stream) {
  (void)in_sizes; (void)n_in; (void)out_size;
  const float* p3 = (const float*)d_in[0];
  const float* p2 = (const float*)d_in[1];
  const float* p1 = (const float*)d_in[2];
  const float* kg1 = (const float*)d_in[3];
  const float* klp = (const float*)d_in[4];
  const float* key_mask = (const float*)d_in[5];
  const float* pre_mask = (const float*)d_in[6];
  const float* conv_top_w = (const float*)d_in[7];
  const float* conv_top_b = (const float*)d_in[8];
  const float* aic_top_w1 = (const float*)d_in[9];
  const float* aic_top_b1 = (const float*)d_in[10];
  const float* aic_top_w2 = (const float*)d_in[11];
  const float* aic_top_b2 = (const float*)d_in[12];
  const float* r1a_w1 = (const float*)d_in[13];
  const float* r1a_b1 = (const float*)d_in[14];
  const float* r1a_w2 = (const float*)d_in[15];
  const float* r1a_b2 = (const float*)d_in[16];
  const float* r1b_w1 = (const float*)d_in[17];
  const float* r1b_b1 = (const float*)d_in[18];
  const float* r1b_w2 = (const float*)d_in[19];
  const float* r1b_b2 = (const float*)d_in[20];
  const float* r2a_w1 = (const float*)d_in[21];
  const float* r2a_b1 = (const float*)d_in[22];
  const float* r2a_w2 = (const float*)d_in[23];
  const float* r2a_b2 = (const float*)d_in[24];
  const float* r2b_w1 = (const float*)d_in[25];
  const float* r2b_b1 = (const float*)d_in[26];
  const float* r2b_w2 = (const float*)d_in[27];
  const float* r2b_b2 = (const float*)d_in[28];
  const float* dec_w = (const float*)d_in[29];
  const float* dec_b = (const float*)d_in[30];
  const float* pred_w = (const float*)d_in[31];
  const float* pred_b = (const float*)d_in[32];
  float* outp = (float*)d_out;

  // workspace layout (float units)
  const size_t OFF_GM = 0;           // 4608
  const size_t OFF_LM = 4608;        // 4608
  const size_t OFF_STAT = 9216;      // 65536
  const size_t OFF_MEAN = 74752;     // 512
  const size_t OFF_INV = 75264;      // 512
  const size_t OFF_R0 = 75776;       // 6,045,696  xcat / yA / zH
  const size_t OFF_R1 = 6121472;     // 4,718,592  yB / zA / zB
  const size_t OFF_A = 10840064;     // 1,179,648  a0 / a1
  const size_t OFF_H48 = 12019712;   // 294,912
  const size_t OFF_H96 = 12314624;   // 1,179,648  h96 / d96
  const size_t OFF_P = 13494272;     // 4,718,592  partials / p2t(bf16) / p1t(f32)
  const size_t OFF_W = 18212864;     // 3,022,848  (6,045,696 ushorts hi+lo)
  const size_t TOTAL_F = 21235712;   // ~85 MB
  if (ws_size < TOTAL_F * sizeof(float)) return;

  float* ws = (float*)d_ws;
  float* gm = ws + OFF_GM;
  float* lm = ws + OFF_LM;
  float* statb = ws + OFF_STAT;
  float* meanb = ws + OFF_MEAN;
  float* invb = ws + OFF_INV;
  float* xcat = ws + OFF_R0;     // NHWC [b][2304][1312]
  float* R0 = ws + OFF_R0;
  float* R1 = ws + OFF_R1;
  float* a0 = ws + OFF_A;
  float* h48 = ws + OFF_H48;
  float* h96 = ws + OFF_H96;
  float* Pbuf = ws + OFF_P;
  ushort_t* p2t = (ushort_t*)(ws + OFF_P + 2359296);
  float* p1t = ws + OFF_P;
  ushort_t* wbh = (ushort_t*)(ws + OFF_W);
  ushort_t* wbl = wbh + 3022848;
  float* a1 = a0;
  float* d96 = h96;

  // pooled masks
  pool8_kernel<<<(2 * 2304 + TPB - 1) / TPB, TPB, 0, stream>>>(key_mask, gm, 2 * 2304);
  pool8_kernel<<<(2 * 2304 + TPB - 1) / TPB, TPB, 0, stream>>>(pre_mask, lm, 2 * 2304);
  // xcat assembly (NHWC)
  topk_global_kernel<<<2 * 2304, TPB, 0, stream>>>(kg1, gm, xcat);
  topk_local_kernel<<<2 * 2304, TPB, 0, stream>>>(klp, lm, xcat);
  tposef_kernel<<<dim3(36, 4, 2), TPB, 0, stream>>>(p3, xcat, 256, 2304, 1312);
  pm_pad_kernel<<<(2 * 2304 * 32 + TPB - 1) / TPB, TPB, 0, stream>>>(lm, xcat);

  // CinW: real weight input-channel count; CIP: padded NHWC stride (CinW rounded to 32
  // except conv_top where xcat is 1312 with zeroed channels 1281..1311)
  auto conv = [&](const float* src, const float* w, const float* bb, float* dst,
                  float* part, int CinW, int CIP, int CoutPad, int CoutReal, int H, int W,
                  int S, int MB, int act) {
    int wtotal = CoutPad * 9 * CIP;
    wconv_kernel<<<(wtotal + TPB - 1) / TPB, TPB, 0, stream>>>(w, wbh, wbl, CinW, CIP,
                                                               CoutReal, wtotal);
    int chunks = CIP / 32;
    int cps = ((chunks + S - 1) / S) * 32;
    dim3 grid((W / 8) * (H / 16), (CoutPad / MB) * S, 2);
    if (MB == 128)
      conv_mfma_kernel<4, 0><<<grid, TPB, 0, stream>>>(src, wbh, wbl, bb, dst, part, CIP,
                                                       CoutPad, H, W, S, cps);
    else if (act == 1)
      conv_mfma_kernel<2, 1><<<grid, TPB, 0, stream>>>(src, wbh, wbl, bb, dst, part, CIP,
                                                       CoutPad, H, W, S, cps);
    else
      conv_mfma_kernel<2, 0><<<grid, TPB, 0, stream>>>(src, wbh, wbl, bb, dst, part, CIP,
                                                       CoutPad, H, W, S, cps);
    if (S > 1) {
      int HW = H * W;
      int total4 = 2 * CoutPad * HW / 4;
      reduce_nhwc_kernel<<<(total4 + TPB - 1) / TPB, TPB, 0, stream>>>(part, bb, dst, S,
                                                                       CoutPad, HW, total4);
    }
  };
  auto inorm = [&](float* x, int C, int N, int resMode, const void* res) {
    dim3 g1(2 * (C / 64), 64);
    in_stats_kernel<<<g1, TPB, 0, stream>>>(x, statb, N, C);
    int Ctot = 2 * C;
    in_final_kernel<<<(Ctot + TPB - 1) / TPB, TPB, 0, stream>>>(statb, meanb, invb, N, Ctot);
    int total4 = 2 * N * C / 4;
    int g = (total4 + TPB - 1) / TPB;
    if (g > 4096) g = 4096;
    if (resMode == 1)
      in_apply_kernel<1><<<g, TPB, 0, stream>>>(x, meanb, invb, res, N, C, total4);
    else if (resMode == 2)
      in_apply_kernel<2><<<g, TPB, 0, stream>>>(x, meanb, invb, res, N, C, total4);
    else
      in_apply_kernel<0><<<g, TPB, 0, stream>>>(x, meanb, invb, res, N, C, total4);
  };

  // ---- top fuse @48 ----
  conv(xcat, conv_top_w, conv_top_b, a0, Pbuf, 1281, 1312, 256, 256, 48, 48, 4, 128, 0);
  conv(a0, aic_top_w1, aic_top_b1, h48, Pbuf, 256, 256, 64, 64, 48, 48, 4, 64, 0);
  inorm(h48, 64, 2304, 0, nullptr);
  conv(h48, aic_top_w2, aic_top_b2, a1, Pbuf, 64, 64, 256, 256, 48, 48, 1, 64, 0);
  inorm(a1, 256, 2304, 0, nullptr);
  // p2 -> NHWC bf16 (after aic partials are dead)
  tposeh_kernel<<<dim3(144, 4, 2), TPB, 0, stream>>>(p2, p2t, 256, 9216, 256);

  // ---- 48 -> 96 ----
  {
    int total4 = 2 * 96 * 96 * 256 / 4;
    int g = (total4 + TPB - 1) / TPB; if (g > 4096) g = 4096;
    resize4_kernel<<<g, TPB, 0, stream>>>(a1, R0, 256, 48, 48, 96, 96, 47.f / 95.f, total4);
  }
  conv(R0, r1a_w1, r1a_b1, h96, Pbuf, 256, 256, 64, 64, 96, 96, 2, 64, 0);
  inorm(h96, 64, 9216, 0, nullptr);
  conv(h96, r1a_w2, r1a_b2, R1, Pbuf, 64, 64, 256, 256, 96, 96, 1, 128, 0);
  inorm(R1, 256, 9216, 1, p2t);
  conv(R1, r1b_w1, r1b_b1, h96, Pbuf, 256, 256, 64, 64, 96, 96, 2, 64, 0);
  inorm(h96, 64, 9216, 0, nullptr);
  conv(h96, r1b_w2, r1b_b2, R0, Pbuf, 64, 64, 256, 256, 96, 96, 1, 128, 0);
  inorm(R0, 256, 9216, 0, nullptr);
  conv(R0, dec_w, dec_b, d96, Pbuf, 256, 256, 64, 64, 96, 96, 2, 64, 0);
  // p1 -> NHWC fp32 (Pbuf now dead)
  tposef_kernel<<<dim3(576, 1, 2), TPB, 0, stream>>>(p1, p1t, 64, 36864, 64);

  // ---- 96 -> 192 ----
  {
    int total4 = 2 * 192 * 192 * 64 / 4;
    int g = (total4 + TPB - 1) / TPB; if (g > 4096) g = 4096;
    resize4_kernel<<<g, TPB, 0, stream>>>(d96, R1, 64, 96, 96, 192, 192, 95.f / 191.f, total4);
  }
  conv(R1, r2a_w1, r2a_b1, R0, nullptr, 64, 64, 64, 64, 192, 192, 1, 64, 0);
  inorm(R0, 64, 36864, 0, nullptr);
  conv(R0, r2a_w2, r2a_b2, R1, nullptr, 64, 64, 64, 64, 192, 192, 1, 64, 0);
  inorm(R1, 64, 36864, 2, p1t);
  conv(R1, r2b_w1, r2b_b1, R0, nullptr, 64, 64, 64, 64, 192, 192, 1, 64, 0);
  inorm(R0, 64, 36864, 0, nullptr);
  conv(R0, r2b_w2, r2b_b2, R1, nullptr, 64, 64, 64, 64, 192, 192, 1, 64, 0);
  inorm(R1, 64, 36864, 0, nullptr);

  // ---- pred head: 64 -> 1 + sigmoid -> d_out (NCHW [2,1,192,192]) ----
  conv(R1, pred_w, pred_b, outp, nullptr, 64, 64, 64, 1, 192, 192, 1, 64, 1);
}

// Round 6
// 1243.927 us; speedup vs baseline: 6.0142x; 1.1763x over previous
//
#include <hip/hip_runtime.h>
#include <math.h>

#define TPB 256

typedef short bh8 __attribute__((ext_vector_type(8)));
typedef float f4 __attribute__((ext_vector_type(4)));
typedef unsigned short ushort_t;

__device__ __forceinline__ unsigned short f2bf(float x) {
  unsigned int u = __float_as_uint(x);
  unsigned int r = (u + 0x7fffu + ((u >> 16) & 1u)) >> 16;
  return (unsigned short)r;
}
__device__ __forceinline__ float bf2f(unsigned short h) {
  return __uint_as_float(((unsigned int)h) << 16);
}
__device__ __forceinline__ unsigned key_of(float x) {
  unsigned u = __float_as_uint(x);
  return u ^ ((u >> 31) ? 0xFFFFFFFFu : 0x80000000u);
}
__device__ __forceinline__ float un_key(unsigned k) {
  unsigned u = k ^ ((k >> 31) ? 0x80000000u : 0xFFFFFFFFu);
  return __uint_as_float(u);
}

// ===== 8x8 max pool: [B,1,384,384] -> [B,2304] =====
__global__ __launch_bounds__(TPB) void pool8_kernel(const float* __restrict__ in,
                                                    float* __restrict__ out, int total) {
  int idx = blockIdx.x * TPB + threadIdx.x;
  if (idx >= total) return;
  int b = idx / 2304, yx = idx - b * 2304;
  int y = yx / 48, x = yx - y * 48;
  const float* p = in + ((size_t)b * 384 + (size_t)y * 8) * 384 + (size_t)x * 8;
  float m = -INFINITY;
#pragma unroll
  for (int i = 0; i < 8; ++i)
#pragma unroll
    for (int j = 0; j < 8; ++j) m = fmaxf(m, p[(size_t)i * 384 + j]);
  out[idx] = m;
}

// ===== global top-k (radix select + bitonic 256), NHWC writes, XCD-chunk swizzle =====
__global__ __launch_bounds__(TPB) void topk_global_kernel(const float* __restrict__ kg1,
                                                          const float* __restrict__ gm,
                                                          float* __restrict__ xcat) {
  __shared__ unsigned histF[256], histB[256];
  __shared__ unsigned soutF[256], soutB[256];
  __shared__ unsigned selT[2], selA[2];
  __shared__ unsigned cntG[2], cntE[2];
  const int tid = threadIdx.x;
  const int lane = tid & 63, wid = tid >> 6;
  int bid = (blockIdx.x & 7) * 576 + (blockIdx.x >> 3);  // XCD-chunked swizzle (4608=8*576)
  int b = bid / 2304, yx = bid - b * 2304;
  const float* kp = kg1 + (size_t)b * 2304 * 2304 + yx;
  const float* gp = gm + (size_t)b * 2304;
  unsigned kF[9], kB[9];
#pragma unroll
  for (int j = 0; j < 9; ++j) {
    int i = tid + 256 * j;
    float v = kp[(size_t)i * 2304];
    float g = gp[i];
    kF[j] = key_of(v * g);
    kB[j] = key_of(v * (1.0f - g));
  }
  unsigned prefF = 0, prefB = 0;
  unsigned KF = 256, KB = 256;
  unsigned gtF = 0, gtB = 0;
#pragma unroll
  for (int p = 0; p < 4; ++p) {
    const int shift = 24 - 8 * p;
    histF[tid] = 0;
    histB[tid] = 0;
    __syncthreads();
#pragma unroll
    for (int j = 0; j < 9; ++j) {
      if (p == 0 || (kF[j] >> (shift + 8)) == prefF)
        atomicAdd(&histF[(kF[j] >> shift) & 0xFFu], 1u);
      if (p == 0 || (kB[j] >> (shift + 8)) == prefB)
        atomicAdd(&histB[(kB[j] >> shift) & 0xFFu], 1u);
    }
    __syncthreads();
    if (wid < 2) {
      unsigned* h = wid ? histB : histF;
      unsigned K = wid ? KB : KF;
      unsigned h0 = h[4 * lane], h1 = h[4 * lane + 1];
      unsigned h2 = h[4 * lane + 2], h3 = h[4 * lane + 3];
      unsigned x = h0 + h1 + h2 + h3;
#pragma unroll
      for (int d = 1; d < 64; d <<= 1) {
        unsigned y = __shfl_down(x, d, 64);
        if (lane + d < 64) x += y;
      }
      unsigned long long m = __ballot(x >= K);
      int tl = 63 - __clzll(m);
      if (lane == tl) {
        unsigned s1 = x - h0, s2 = s1 - h1, s3 = s2 - h2, s4 = s3 - h3;
        int jj;
        unsigned A;
        if (s3 >= K) { jj = 3; A = s4; }
        else if (s2 >= K) { jj = 2; A = s3; }
        else if (s1 >= K) { jj = 1; A = s2; }
        else { jj = 0; A = s1; }
        selT[wid] = 4 * tl + jj;
        selA[wid] = A;
      }
    }
    __syncthreads();
    unsigned TF = selT[0], AF = selA[0];
    unsigned TB = selT[1], AB = selA[1];
    prefF = (prefF << 8) | TF; gtF += AF; KF -= AF;
    prefB = (prefB << 8) | TB; gtB += AB; KB -= AB;
    __syncthreads();
  }
  const unsigned tF = prefF, tB = prefB;
  const unsigned nGTF = gtF, needF = KF;
  const unsigned nGTB = gtB, needB = KB;
  if (tid == 0) { cntG[0] = 0; cntG[1] = 0; cntE[0] = 0; cntE[1] = 0; }
  __syncthreads();
#pragma unroll
  for (int j = 0; j < 9; ++j) {
    unsigned k = kF[j];
    if (k > tF) soutF[atomicAdd(&cntG[0], 1u)] = k;
    else if (k == tF) {
      unsigned e = atomicAdd(&cntE[0], 1u);
      if (e < needF) soutF[nGTF + e] = tF;
    }
    k = kB[j];
    if (k > tB) soutB[atomicAdd(&cntG[1], 1u)] = k;
    else if (k == tB) {
      unsigned e = atomicAdd(&cntE[1], 1u);
      if (e < needB) soutB[nGTB + e] = tB;
    }
  }
  __syncthreads();
  for (int kk = 2; kk <= 256; kk <<= 1) {
    for (int j = kk >> 1; j > 0; j >>= 1) {
      int t = tid, ixj = t ^ j;
      if (ixj > t) {
        bool up = ((t & kk) == 0);
        unsigned a = soutF[t], c = soutF[ixj];
        if (up ? (a > c) : (a < c)) { soutF[t] = c; soutF[ixj] = a; }
        a = soutB[t]; c = soutB[ixj];
        if (up ? (a > c) : (a < c)) { soutB[t] = c; soutB[ixj] = a; }
      }
      __syncthreads();
    }
  }
  size_t base = ((size_t)(b * 2304 + yx)) * 1312;
  xcat[base + 256 + tid] = un_key(soutF[255 - tid]);
  xcat[base + 512 + tid] = un_key(soutB[255 - tid]);
}

// ===== local top-k (fused bitonic over 512), NHWC writes =====
__global__ __launch_bounds__(TPB) void topk_local_kernel(const float* __restrict__ klp,
                                                         const float* __restrict__ lm,
                                                         float* __restrict__ xcat) {
  __shared__ float sf[512];
  __shared__ float sb[512];
  const int tid = threadIdx.x;
  int bid = (blockIdx.x & 7) * 576 + (blockIdx.x >> 3);
  int b = bid / 2304, yx = bid - b * 2304;
  int y = yx / 48, x = yx - y * 48;
  for (int i = tid; i < 512; i += TPB) {
    float vf = -INFINITY, vb = -INFINITY;
    if (i < 289) {
      int dy = i / 17, dx = i - dy * 17;
      int sy = y + dy - 8, sx = x + dx - 8;
      float pv = 0.f;
      if (sy >= 0 && sy < 48 && sx >= 0 && sx < 48) pv = lm[(size_t)b * 2304 + sy * 48 + sx];
      float v = klp[((size_t)b * 289 + i) * 2304 + yx];
      vf = v * pv;
      vb = v * (1.0f - pv);
    }
    sf[i] = vf;
    sb[i] = vb;
  }
  for (int k = 2; k <= 512; k <<= 1) {
    for (int j = k >> 1; j > 0; j >>= 1) {
      __syncthreads();
      for (int t = tid; t < 512; t += TPB) {
        int ixj = t ^ j;
        if (ixj > t) {
          bool up = ((t & k) == 0);
          float a = sf[t], c = sf[ixj];
          if (up ? (a > c) : (a < c)) { sf[t] = c; sf[ixj] = a; }
          a = sb[t]; c = sb[ixj];
          if (up ? (a > c) : (a < c)) { sb[t] = c; sb[ixj] = a; }
        }
      }
    }
  }
  __syncthreads();
  size_t base = ((size_t)(b * 2304 + yx)) * 1312;
  xcat[base + 768 + tid] = sf[511 - tid];
  xcat[base + 1024 + tid] = sb[511 - tid];
}

// ===== NCHW fp32 -> NHWC fp32 transpose (64c x 64px LDS tiles) =====
__global__ __launch_bounds__(TPB) void tposef_kernel(const float* __restrict__ src,
                                                     float* __restrict__ dst, int C, int HW,
                                                     int DS) {
  __shared__ float tile[64][65];
  int px0 = blockIdx.x * 64;
  int c0 = blockIdx.y * 64;
  int b = blockIdx.z;
  int tid = threadIdx.x;
#pragma unroll
  for (int i = 0; i < 16; ++i) {
    int c = (tid >> 6) + i * 4, p = tid & 63;
    tile[c][p] = src[((size_t)b * C + c0 + c) * HW + px0 + p];
  }
  __syncthreads();
#pragma unroll
  for (int i = 0; i < 16; ++i) {
    int c = tid & 63, p = (tid >> 6) + i * 4;
    dst[((size_t)b * HW + px0 + p) * DS + c0 + c] = tile[c][p];
  }
}

// ===== NCHW fp32 -> NHWC bf16 transpose =====
__global__ __launch_bounds__(TPB) void tposeh_kernel(const float* __restrict__ src,
                                                     ushort_t* __restrict__ dst, int C, int HW,
                                                     int DS) {
  __shared__ float tile[64][65];
  int px0 = blockIdx.x * 64;
  int c0 = blockIdx.y * 64;
  int b = blockIdx.z;
  int tid = threadIdx.x;
#pragma unroll
  for (int i = 0; i < 16; ++i) {
    int c = (tid >> 6) + i * 4, p = tid & 63;
    tile[c][p] = src[((size_t)b * C + c0 + c) * HW + px0 + p];
  }
  __syncthreads();
#pragma unroll
  for (int i = 0; i < 16; ++i) {
    int c = tid & 63, p = (tid >> 6) + i * 4;
    dst[((size_t)b * HW + px0 + p) * DS + c0 + c] = f2bf(tile[c][p]);
  }
}

// ===== pm channel + zero pad channels of xcat =====
__global__ __launch_bounds__(TPB) void pm_pad_kernel(const float* __restrict__ lm,
                                                     float* __restrict__ xcat) {
  int idx = blockIdx.x * TPB + threadIdx.x;
  if (idx >= 2 * 2304 * 32) return;
  int ch = idx & 31;
  int r = idx >> 5;  // b*2304+yx
  xcat[(size_t)r * 1312 + 1280 + ch] = (ch == 0) ? lm[r] : 0.f;
}

// ===== weight preconvert: OIHW fp32 -> wave-coalesced A-frag layout, split bf16 =====
// layout: [chunk][kykx][cog16][lane(=hi4*16+lo16)][8]; co=cog*16+lo16, ci=chunk*32+hi4*8+e
__global__ __launch_bounds__(TPB) void wconv_kernel(const float* __restrict__ w,
                                                    ushort_t* __restrict__ whi,
                                                    ushort_t* __restrict__ wlo,
                                                    int CinW, int CIP, int CoutPad,
                                                    int CoutReal, int total) {
  int i = blockIdx.x * TPB + threadIdx.x;
  if (i >= total) return;
  int e = i & 7;
  int t = i >> 3;
  int l16 = t & 15; t >>= 4;
  int h4 = t & 3; t >>= 2;
  int NCOG = CoutPad >> 4;
  int cog = t % NCOG; t /= NCOG;
  int kykx = t % 9;
  int chunk = t / 9;
  int co = cog * 16 + l16;
  int ci = chunk * 32 + h4 * 8 + e;
  float v = 0.f;
  if (ci < CinW && co < CoutReal) v = w[((size_t)co * CinW + ci) * 9 + kykx];
  unsigned short h = f2bf(v);
  whi[i] = h;
  wlo[i] = f2bf(v - bf2f(h));
}

// ===== MFMA implicit-GEMM 3x3 conv, NHWC, split-bf16 3-term =====
// tile: MB co x 128 px (16 rows x 8 cols); halo 18x10 staged per 32-ci chunk in LDS.
// MFR = MB/32 (2 or 4). ACT: 0 = bias+store NHWC (or partial), 1 = pred sigmoid, co0 only.
template <int MFR, int ACT>
__global__ __launch_bounds__(TPB) void conv_mfma_kernel(
    const float* __restrict__ in, const ushort_t* __restrict__ whi,
    const ushort_t* __restrict__ wlo, const float* __restrict__ bias,
    float* __restrict__ outp, float* __restrict__ partial,
    int CIP, int Cout, int H, int W, int S, int ci_per_s) {
  __shared__ unsigned sH[3600];  // [180 px][20 words] bf16-hi (16 used)
  __shared__ unsigned sL[3600];
  const int MB = MFR * 32;
  const int tid = threadIdx.x;
  const int lane = tid & 63, wid = tid >> 6;
  const int lo16 = lane & 15, hi4 = lane >> 4;
  const int wco = wid & 1, wpx = wid >> 1;
  const int tilesX = W >> 3;
  const int tx0 = (blockIdx.x % tilesX) << 3;
  const int ty0 = (blockIdx.x / tilesX) << 4;
  const int s = blockIdx.y % S;
  const int co0 = (blockIdx.y / S) * MB;
  const int b = blockIdx.z;
  const int NCOG = Cout >> 4;
  const size_t HW = (size_t)H * W;
  const float* inb = in + (size_t)b * HW * CIP;
  int ci_begin = s * ci_per_s;
  int ci_end = ci_begin + ci_per_s;
  if (ci_end > CIP) ci_end = CIP;
  f4 acc[MFR][4];
#pragma unroll
  for (int m = 0; m < MFR; ++m)
#pragma unroll
    for (int n = 0; n < 4; ++n) acc[m][n] = (f4){0.f, 0.f, 0.f, 0.f};

  for (int ci0 = ci_begin; ci0 < ci_end; ci0 += 32) {
    __syncthreads();
    // stage 180 px x 32 ci (fp32 NHWC -> split bf16, packed 2/word)
#pragma unroll
    for (int it = 0; it < 6; ++it) {
      int u = tid + it * TPB;
      if (u < 1440) {
        int px = u >> 3, q = u & 7;
        int prow = px / 10, pcol = px - prow * 10;
        int gy = ty0 - 1 + prow, gx = tx0 - 1 + pcol;
        float4 v = {0.f, 0.f, 0.f, 0.f};
        if (gy >= 0 && gy < H && gx >= 0 && gx < W)
          v = *(const float4*)(inb + ((size_t)gy * W + gx) * CIP + ci0 + q * 4);
        unsigned short h0 = f2bf(v.x), h1 = f2bf(v.y), h2 = f2bf(v.z), h3 = f2bf(v.w);
        unsigned short l0 = f2bf(v.x - bf2f(h0)), l1 = f2bf(v.y - bf2f(h1));
        unsigned short l2 = f2bf(v.z - bf2f(h2)), l3 = f2bf(v.w - bf2f(h3));
        uint2 hw = {(unsigned)h0 | ((unsigned)h1 << 16), (unsigned)h2 | ((unsigned)h3 << 16)};
        uint2 lw = {(unsigned)l0 | ((unsigned)l1 << 16), (unsigned)l2 | ((unsigned)l3 << 16)};
        *(uint2*)&sH[px * 20 + q * 2] = hw;
        *(uint2*)&sL[px * 20 + q * 2] = lw;
      }
    }
    __syncthreads();
    const int chunkIdx = ci0 >> 5;
#pragma unroll
    for (int ky = 0; ky < 3; ++ky) {
#pragma unroll
      for (int kx = 0; kx < 3; ++kx) {
        const int kykx = ky * 3 + kx;
        bh8 bh[4], bl[4];
#pragma unroll
        for (int n = 0; n < 4; ++n) {
          int pix = (wpx * 8 + n * 2 + (lo16 >> 3) + ky) * 10 + (lo16 & 7) + kx;
          union { uint4 q; bh8 v; } ub, ul;
          ub.q = *(const uint4*)&sH[pix * 20 + 4 * hi4];
          ul.q = *(const uint4*)&sL[pix * 20 + 4 * hi4];
          bh[n] = ub.v;
          bl[n] = ul.v;
        }
#pragma unroll
        for (int m = 0; m < MFR; ++m) {
          int cog = (co0 + wco * (MB / 2) + m * 16) >> 4;
          size_t woff = (((size_t)chunkIdx * 9 + kykx) * NCOG + cog) * 512 + (size_t)lane * 8;
          bh8 ah = *(const bh8*)(whi + woff);
          bh8 al = *(const bh8*)(wlo + woff);
#pragma unroll
          for (int n = 0; n < 4; ++n) {
            acc[m][n] = __builtin_amdgcn_mfma_f32_16x16x32_bf16(ah, bh[n], acc[m][n], 0, 0, 0);
            acc[m][n] = __builtin_amdgcn_mfma_f32_16x16x32_bf16(ah, bl[n], acc[m][n], 0, 0, 0);
            acc[m][n] = __builtin_amdgcn_mfma_f32_16x16x32_bf16(al, bh[n], acc[m][n], 0, 0, 0);
          }
        }
      }
    }
  }

#pragma unroll
  for (int m = 0; m < MFR; ++m) {
#pragma unroll
    for (int n = 0; n < 4; ++n) {
      int py = ty0 + wpx * 8 + n * 2 + (lo16 >> 3);
      int pxx = tx0 + (lo16 & 7);
      int co_r0 = co0 + wco * (MB / 2) + m * 16 + hi4 * 4;
      if (ACT == 1) {
        if (wco == 0 && m == 0 && hi4 == 0) {
          float v = acc[0][n][0] + bias[0];
          outp[(size_t)b * HW + (size_t)py * W + pxx] = 1.0f / (1.0f + expf(-v));
        }
      } else if (S == 1) {
        float4 bv = *(const float4*)(bias + co_r0);
        float4 o = {acc[m][n][0] + bv.x, acc[m][n][1] + bv.y, acc[m][n][2] + bv.z,
                    acc[m][n][3] + bv.w};
        *(float4*)(outp + (((size_t)b * HW + (size_t)py * W + pxx) * Cout + co_r0)) = o;
      } else {
        float4 o = {acc[m][n][0], acc[m][n][1], acc[m][n][2], acc[m][n][3]};
        *(float4*)(partial + (((size_t)(s * 2 + b) * HW + (size_t)py * W + pxx) * Cout + co_r0)) = o;
      }
    }
  }
}

// ===== split-K reduce + bias (NHWC) =====
// NOTE: outp may alias one partial slice element-exclusively (each thread writes only
// the element it read) — safe by data dependence.
__global__ __launch_bounds__(TPB) void reduce_nhwc_kernel(const float* __restrict__ partial,
                                                          const float* __restrict__ bias,
                                                          float* __restrict__ outp, int S,
                                                          int Cout, int HW, int total4) {
  int i = blockIdx.x * TPB + threadIdx.x;
  if (i >= total4) return;
  int e = i * 4;
  int CHW = Cout * HW;
  int b = e / CHW;
  int rem = e - b * CHW;
  int co = e % Cout;
  float4 acc = {0.f, 0.f, 0.f, 0.f};
  for (int ss = 0; ss < S; ++ss) {
    const float4 t = *(const float4*)(partial + (size_t)(ss * 2 + b) * CHW + rem);
    acc.x += t.x; acc.y += t.y; acc.z += t.z; acc.w += t.w;
  }
  float4 bv = *(const float4*)(bias + co);
  float4 o = {acc.x + bv.x, acc.y + bv.y, acc.z + bv.z, acc.w + bv.w};
  *(float4*)(outp + (size_t)b * CHW + rem) = o;
}

// ===== InstanceNorm NHWC: stats (64 slices) -> finalize -> apply(+res+relu) =====
__global__ __launch_bounds__(TPB) void in_stats_kernel(const float* __restrict__ x,
                                                       float* __restrict__ stat, int N, int C) {
  __shared__ float ls[4][64], lq[4][64];
  int CG = C >> 6;
  int b = blockIdx.x / CG, cg = blockIdx.x % CG;
  int slice = blockIdx.y;
  int c = threadIdx.x & 63, p = threadIdx.x >> 6;
  int cnt = N >> 6;
  int base = slice * cnt;
  float s = 0.f, q = 0.f;
  const float* xp = x + ((size_t)b * N) * C + cg * 64 + c;
  for (int px = base + p; px < base + cnt; px += 4) {
    float v = xp[(size_t)px * C];
    s += v;
    q = fmaf(v, v, q);
  }
  ls[p][c] = s;
  lq[p][c] = q;
  __syncthreads();
  if (threadIdx.x < 64) {
    float S = ls[0][threadIdx.x] + ls[1][threadIdx.x] + ls[2][threadIdx.x] + ls[3][threadIdx.x];
    float Q = lq[0][threadIdx.x] + lq[1][threadIdx.x] + lq[2][threadIdx.x] + lq[3][threadIdx.x];
    int Ctot = 2 * C;
    int idx = b * C + cg * 64 + threadIdx.x;
    stat[(size_t)(slice * Ctot + idx) * 2] = S;
    stat[(size_t)(slice * Ctot + idx) * 2 + 1] = Q;
  }
}

__global__ __launch_bounds__(TPB) void in_final_kernel(const float* __restrict__ stat,
                                                       float* __restrict__ mean,
                                                       float* __restrict__ inv, int N, int Ctot) {
  int idx = blockIdx.x * TPB + threadIdx.x;
  if (idx >= Ctot) return;
  float S = 0.f, Q = 0.f;
  for (int sl = 0; sl < 64; ++sl) {
    S += stat[(size_t)(sl * Ctot + idx) * 2];
    Q += stat[(size_t)(sl * Ctot + idx) * 2 + 1];
  }
  float m = S / (float)N;
  float var = Q / (float)N - m * m;
  if (var < 0.f) var = 0.f;
  mean[idx] = m;
  inv[idx] = 1.0f / sqrtf(var + 1e-5f);
}

// RES: 0 none, 1 bf16 residual, 2 fp32 residual
template <int RES>
__global__ __launch_bounds__(TPB) void in_apply_kernel(float* __restrict__ x,
                                                       const float* __restrict__ mean,
                                                       const float* __restrict__ inv,
                                                       const void* __restrict__ res, int N,
                                                       int C, int total4) {
  int NC = N * C;
  for (int i = blockIdx.x * TPB + threadIdx.x; i < total4; i += gridDim.x * TPB) {
    int e = i * 4;
    int c = e % C;
    int b = e / NC;
    int midx = b * C + c;
    float4 m4 = *(const float4*)(mean + midx);
    float4 i4 = *(const float4*)(inv + midx);
    float4 v = *(float4*)(x + e);
    float4 o;
    o.x = fmaxf((v.x - m4.x) * i4.x, 0.f);
    o.y = fmaxf((v.y - m4.y) * i4.y, 0.f);
    o.z = fmaxf((v.z - m4.z) * i4.z, 0.f);
    o.w = fmaxf((v.w - m4.w) * i4.w, 0.f);
    if (RES == 1) {
      const ushort_t* r = (const ushort_t*)res + e;
      o.x += bf2f(r[0]); o.y += bf2f(r[1]); o.z += bf2f(r[2]); o.w += bf2f(r[3]);
    } else if (RES == 2) {
      const float4 r = *(const float4*)((const float*)res + e);
      o.x += r.x; o.y += r.y; o.z += r.z; o.w += r.w;
    }
    *(float4*)(x + e) = o;
  }
}

// ===== bilinear resize align_corners, NHWC, float4 over channels =====
__global__ __launch_bounds__(TPB) void resize4_kernel(const float* __restrict__ in,
                                                      float* __restrict__ out, int C, int hin,
                                                      int win, int Hout, int Wout, float r,
                                                      int total4) {
  for (int i = blockIdx.x * TPB + threadIdx.x; i < total4; i += gridDim.x * TPB) {
    int e = i * 4;
    int c = e % C;
    int t = e / C;
    int X = t % Wout;
    int t2 = t / Wout;
    int Y = t2 % Hout;
    int b = t2 / Hout;
    float ys = Y * r, xs = X * r;
    int y0 = (int)floorf(ys);
    if (y0 > hin - 1) y0 = hin - 1;
    int x0 = (int)floorf(xs);
    if (x0 > win - 1) x0 = win - 1;
    int y1 = y0 + 1 < hin ? y0 + 1 : hin - 1;
    int x1 = x0 + 1 < win ? x0 + 1 : win - 1;
    float wy = ys - (float)y0, wx = xs - (float)x0;
    const float* ip = in + ((size_t)b * hin * win) * C + c;
    float4 a = *(const float4*)(ip + ((size_t)y0 * win + x0) * C);
    float4 bb = *(const float4*)(ip + ((size_t)y0 * win + x1) * C);
    float4 cc = *(const float4*)(ip + ((size_t)y1 * win + x0) * C);
    float4 d = *(const float4*)(ip + ((size_t)y1 * win + x1) * C);
    float4 o;
    o.x = (a.x * (1.f - wy) + cc.x * wy) * (1.f - wx) + (bb.x * (1.f - wy) + d.x * wy) * wx;
    o.y = (a.y * (1.f - wy) + cc.y * wy) * (1.f - wx) + (bb.y * (1.f - wy) + d.y * wy) * wx;
    o.z = (a.z * (1.f - wy) + cc.z * wy) * (1.f - wx) + (bb.z * (1.f - wy) + d.z * wy) * wx;
    o.w = (a.w * (1.f - wy) + cc.w * wy) * (1.f - wx) + (bb.w * (1.f - wy) + d.w * wy) * wx;
    *(float4*)(out + e) = o;
  }
}

extern "C" void kernel_launch(void* const* d_in, const int* in_sizes, int n_in,
                              void* d_out, int out_size, void* d_ws, size_t ws_size,
                              hipStream_t stream) {
  (void)in_sizes; (void)n_in; (void)out_size;
  const float* p3 = (const float*)d_in[0];
  const float* p2 = (const float*)d_in[1];
  const float* p1 = (const float*)d_in[2];
  const float* kg1 = (const float*)d_in[3];
  const float* klp = (const float*)d_in[4];
  const float* key_mask = (const float*)d_in[5];
  const float* pre_mask = (const float*)d_in[6];
  const float* conv_top_w = (const float*)d_in[7];
  const float* conv_top_b = (const float*)d_in[8];
  const float* aic_top_w1 = (const float*)d_in[9];
  const float* aic_top_b1 = (const float*)d_in[10];
  const float* aic_top_w2 = (const float*)d_in[11];
  const float* aic_top_b2 = (const float*)d_in[12];
  const float* r1a_w1 = (const float*)d_in[13];
  const float* r1a_b1 = (const float*)d_in[14];
  const float* r1a_w2 = (const float*)d_in[15];
  const float* r1a_b2 = (const float*)d_in[16];
  const float* r1b_w1 = (const float*)d_in[17];
  const float* r1b_b1 = (const float*)d_in[18];
  const float* r1b_w2 = (const float*)d_in[19];
  const float* r1b_b2 = (const float*)d_in[20];
  const float* r2a_w1 = (const float*)d_in[21];
  const float* r2a_b1 = (const float*)d_in[22];
  const float* r2a_w2 = (const float*)d_in[23];
  const float* r2a_b2 = (const float*)d_in[24];
  const float* r2b_w1 = (const float*)d_in[25];
  const float* r2b_b1 = (const float*)d_in[26];
  const float* r2b_w2 = (const float*)d_in[27];
  const float* r2b_b2 = (const float*)d_in[28];
  const float* dec_w = (const float*)d_in[29];
  const float* dec_b = (const float*)d_in[30];
  const float* pred_w = (const float*)d_in[31];
  const float* pred_b = (const float*)d_in[32];
  float* outp = (float*)d_out;

  // workspace layout (float units)
  const size_t OFF_GM = 0;           // 4608
  const size_t OFF_LM = 4608;        // 4608
  const size_t OFF_STAT = 9216;      // 65536
  const size_t OFF_MEAN = 74752;     // 512
  const size_t OFF_INV = 75264;      // 512
  const size_t OFF_R0 = 75776;       // 6,045,696  xcat / yA / zH / p2t(bf16 window)
  const size_t OFF_R1 = 6121472;     // 4,718,592  yB / zA  (+conv_top partial spans R1..P)
  const size_t OFF_A = 10840064;     // 1,179,648  a0 / a1
  const size_t OFF_H48 = 12019712;   // 294,912
  const size_t OFF_H96 = 12314624;   // 1,179,648  h96 / d96
  const size_t OFF_P = 13494272;     // 4,718,592  partials / p1t(f32)
  const size_t OFF_W = 18212864;     // 3,022,848  (6,045,696 ushorts hi+lo)
  const size_t TOTAL_F = 21235712;   // ~85 MB
  if (ws_size < TOTAL_F * sizeof(float)) return;

  float* ws = (float*)d_ws;
  float* gm = ws + OFF_GM;
  float* lm = ws + OFF_LM;
  float* statb = ws + OFF_STAT;
  float* meanb = ws + OFF_MEAN;
  float* invb = ws + OFF_INV;
  float* xcat = ws + OFF_R0;     // NHWC [b][2304][1312]
  float* R0 = ws + OFF_R0;
  float* R1 = ws + OFF_R1;
  float* a0 = ws + OFF_A;
  float* h48 = ws + OFF_H48;
  float* h96 = ws + OFF_H96;
  float* Pbuf = ws + OFF_P;
  float* PbufTop = ws + OFF_R1;  // conv_top S=8 partial: 9.44M floats spanning R1..P[2.1M]
                                 // (a0 aliases slot ss=4,b — element-exclusive in reduce)
  ushort_t* p2t = (ushort_t*)R0; // written after r1a_w1 (yA dead), dead before r1b_w2
  float* p1t = ws + OFF_P;
  ushort_t* wbh = (ushort_t*)(ws + OFF_W);
  ushort_t* wbl = wbh + 3022848;
  float* a1 = a0;
  float* d96 = h96;

  // pooled masks
  pool8_kernel<<<(2 * 2304 + TPB - 1) / TPB, TPB, 0, stream>>>(key_mask, gm, 2 * 2304);
  pool8_kernel<<<(2 * 2304 + TPB - 1) / TPB, TPB, 0, stream>>>(pre_mask, lm, 2 * 2304);
  // xcat assembly (NHWC)
  topk_global_kernel<<<2 * 2304, TPB, 0, stream>>>(kg1, gm, xcat);
  topk_local_kernel<<<2 * 2304, TPB, 0, stream>>>(klp, lm, xcat);
  tposef_kernel<<<dim3(36, 4, 2), TPB, 0, stream>>>(p3, xcat, 256, 2304, 1312);
  pm_pad_kernel<<<(2 * 2304 * 32 + TPB - 1) / TPB, TPB, 0, stream>>>(lm, xcat);

  auto conv = [&](const float* src, const float* w, const float* bb, float* dst,
                  float* part, int CinW, int CIP, int CoutPad, int CoutReal, int H, int W,
                  int S, int MB, int act) {
    int wtotal = CoutPad * 9 * CIP;
    wconv_kernel<<<(wtotal + TPB - 1) / TPB, TPB, 0, stream>>>(w, wbh, wbl, CinW, CIP,
                                                               CoutPad, CoutReal, wtotal);
    int chunks = CIP / 32;
    int cps = ((chunks + S - 1) / S) * 32;
    dim3 grid((W / 8) * (H / 16), (CoutPad / MB) * S, 2);
    if (MB == 128)
      conv_mfma_kernel<4, 0><<<grid, TPB, 0, stream>>>(src, wbh, wbl, bb, dst, part, CIP,
                                                       CoutPad, H, W, S, cps);
    else if (act == 1)
      conv_mfma_kernel<2, 1><<<grid, TPB, 0, stream>>>(src, wbh, wbl, bb, dst, part, CIP,
                                                       CoutPad, H, W, S, cps);
    else
      conv_mfma_kernel<2, 0><<<grid, TPB, 0, stream>>>(src, wbh, wbl, bb, dst, part, CIP,
                                                       CoutPad, H, W, S, cps);
    if (S > 1) {
      int HW = H * W;
      int total4 = 2 * CoutPad * HW / 4;
      reduce_nhwc_kernel<<<(total4 + TPB - 1) / TPB, TPB, 0, stream>>>(part, bb, dst, S,
                                                                       CoutPad, HW, total4);
    }
  };
  auto inorm = [&](float* x, int C, int N, int resMode, const void* res) {
    dim3 g1(2 * (C / 64), 64);
    in_stats_kernel<<<g1, TPB, 0, stream>>>(x, statb, N, C);
    int Ctot = 2 * C;
    in_final_kernel<<<(Ctot + TPB - 1) / TPB, TPB, 0, stream>>>(statb, meanb, invb, N, Ctot);
    int total4 = 2 * N * C / 4;
    int g = (total4 + TPB - 1) / TPB;
    if (g > 4096) g = 4096;
    if (resMode == 1)
      in_apply_kernel<1><<<g, TPB, 0, stream>>>(x, meanb, invb, res, N, C, total4);
    else if (resMode == 2)
      in_apply_kernel<2><<<g, TPB, 0, stream>>>(x, meanb, invb, res, N, C, total4);
    else
      in_apply_kernel<0><<<g, TPB, 0, stream>>>(x, meanb, invb, res, N, C, total4);
  };

  // ---- top fuse @48 ----
  conv(xcat, conv_top_w, conv_top_b, a0, PbufTop, 1281, 1312, 256, 256, 48, 48, 8, 128, 0);
  conv(a0, aic_top_w1, aic_top_b1, h48, Pbuf, 256, 256, 64, 64, 48, 48, 8, 64, 0);
  inorm(h48, 64, 2304, 0, nullptr);
  conv(h48, aic_top_w2, aic_top_b2, a1, Pbuf, 64, 64, 256, 256, 48, 48, 2, 64, 0);
  inorm(a1, 256, 2304, 0, nullptr);

  // ---- 48 -> 96 ----
  {
    int total4 = 2 * 96 * 96 * 256 / 4;
    int g = (total4 + TPB - 1) / TPB; if (g > 4096) g = 4096;
    resize4_kernel<<<g, TPB, 0, stream>>>(a1, R0, 256, 48, 48, 96, 96, 47.f / 95.f, total4);
  }
  conv(R0, r1a_w1, r1a_b1, h96, Pbuf, 256, 256, 64, 64, 96, 96, 4, 64, 0);
  // p2 -> NHWC bf16 into R0 window (yA consumed by r1a_w1 above)
  tposeh_kernel<<<dim3(144, 4, 2), TPB, 0, stream>>>(p2, p2t, 256, 9216, 256);
  inorm(h96, 64, 9216, 0, nullptr);
  conv(h96, r1a_w2, r1a_b2, R1, nullptr, 64, 64, 256, 256, 96, 96, 1, 64, 0);
  inorm(R1, 256, 9216, 1, p2t);
  conv(R1, r1b_w1, r1b_b1, h96, Pbuf, 256, 256, 64, 64, 96, 96, 4, 64, 0);
  inorm(h96, 64, 9216, 0, nullptr);
  conv(h96, r1b_w2, r1b_b2, R0, nullptr, 64, 64, 256, 256, 96, 96, 1, 64, 0);
  inorm(R0, 256, 9216, 0, nullptr);
  conv(R0, dec_w, dec_b, d96, Pbuf, 256, 256, 64, 64, 96, 96, 4, 64, 0);
  // p1 -> NHWC fp32 (Pbuf partials consumed by dec's reduce)
  tposef_kernel<<<dim3(576, 1, 2), TPB, 0, stream>>>(p1, p1t, 64, 36864, 64);

  // ---- 96 -> 192 ----
  {
    int total4 = 2 * 192 * 192 * 64 / 4;
    int g = (total4 + TPB - 1) / TPB; if (g > 4096) g = 4096;
    resize4_kernel<<<g, TPB, 0, stream>>>(d96, R1, 64, 96, 96, 192, 192, 95.f / 191.f, total4);
  }
  conv(R1, r2a_w1, r2a_b1, R0, nullptr, 64, 64, 64, 64, 192, 192, 1, 64, 0);
  inorm(R0, 64, 36864, 0, nullptr);
  conv(R0, r2a_w2, r2a_b2, R1, nullptr, 64, 64, 64, 64, 192, 192, 1, 64, 0);
  inorm(R1, 64, 36864, 2, p1t);
  conv(R1, r2b_w1, r2b_b1, R0, nullptr, 64, 64, 64, 64, 192, 192, 1, 64, 0);
  inorm(R0, 64, 36864, 0, nullptr);
  conv(R0, r2b_w2, r2b_b2, R1, nullptr, 64, 64, 64, 64, 192, 192, 1, 64, 0);
  inorm(R1, 64, 36864, 0, nullptr);

  // ---- pred head: 64 -> 1 + sigmoid -> d_out (NCHW [2,1,192,192]) ----
  conv(R1, pred_w, pred_b, outp, nullptr, 64, 64, 64, 1, 192, 192, 1, 64, 1);
}

// Round 7
// 932.392 us; speedup vs baseline: 8.0237x; 1.3341x over previous
//
#include <hip/hip_runtime.h>
#include <math.h>

#define TPB 256

typedef short bh8 __attribute__((ext_vector_type(8)));
typedef float f4 __attribute__((ext_vector_type(4)));
typedef unsigned short ushort_t;

__device__ __forceinline__ unsigned short f2bf(float x) {
  unsigned int u = __float_as_uint(x);
  unsigned int r = (u + 0x7fffu + ((u >> 16) & 1u)) >> 16;
  return (unsigned short)r;
}
__device__ __forceinline__ float bf2f(unsigned short h) {
  return __uint_as_float(((unsigned int)h) << 16);
}
__device__ __forceinline__ unsigned key_of(float x) {
  unsigned u = __float_as_uint(x);
  return u ^ ((u >> 31) ? 0xFFFFFFFFu : 0x80000000u);
}
__device__ __forceinline__ float un_key(unsigned k) {
  unsigned u = k ^ ((k >> 31) ? 0x80000000u : 0xFFFFFFFFu);
  return __uint_as_float(u);
}

// ===== 8x8 max pool =====
__global__ __launch_bounds__(TPB) void pool8_kernel(const float* __restrict__ in,
                                                    float* __restrict__ out, int total) {
  int idx = blockIdx.x * TPB + threadIdx.x;
  if (idx >= total) return;
  int b = idx / 2304, yx = idx - b * 2304;
  int y = yx / 48, x = yx - y * 48;
  const float* p = in + ((size_t)b * 384 + (size_t)y * 8) * 384 + (size_t)x * 8;
  float m = -INFINITY;
#pragma unroll
  for (int i = 0; i < 8; ++i)
#pragma unroll
    for (int j = 0; j < 8; ++j) m = fmaxf(m, p[(size_t)i * 384 + j]);
  out[idx] = m;
}

// ===== global top-k (radix select + bitonic 256) -> bf16 NHWC =====
__global__ __launch_bounds__(TPB) void topk_global_kernel(const float* __restrict__ kg1,
                                                          const float* __restrict__ gm,
                                                          ushort_t* __restrict__ xcat) {
  __shared__ unsigned histF[256], histB[256];
  __shared__ unsigned soutF[256], soutB[256];
  __shared__ unsigned selT[2], selA[2];
  __shared__ unsigned cntG[2], cntE[2];
  const int tid = threadIdx.x;
  const int lane = tid & 63, wid = tid >> 6;
  int bid = (blockIdx.x & 7) * 576 + (blockIdx.x >> 3);
  int b = bid / 2304, yx = bid - b * 2304;
  const float* kp = kg1 + (size_t)b * 2304 * 2304 + yx;
  const float* gp = gm + (size_t)b * 2304;
  unsigned kF[9], kB[9];
#pragma unroll
  for (int j = 0; j < 9; ++j) {
    int i = tid + 256 * j;
    float v = kp[(size_t)i * 2304];
    float g = gp[i];
    kF[j] = key_of(v * g);
    kB[j] = key_of(v * (1.0f - g));
  }
  unsigned prefF = 0, prefB = 0;
  unsigned KF = 256, KB = 256;
  unsigned gtF = 0, gtB = 0;
#pragma unroll
  for (int p = 0; p < 4; ++p) {
    const int shift = 24 - 8 * p;
    histF[tid] = 0;
    histB[tid] = 0;
    __syncthreads();
#pragma unroll
    for (int j = 0; j < 9; ++j) {
      if (p == 0 || (kF[j] >> (shift + 8)) == prefF)
        atomicAdd(&histF[(kF[j] >> shift) & 0xFFu], 1u);
      if (p == 0 || (kB[j] >> (shift + 8)) == prefB)
        atomicAdd(&histB[(kB[j] >> shift) & 0xFFu], 1u);
    }
    __syncthreads();
    if (wid < 2) {
      unsigned* h = wid ? histB : histF;
      unsigned K = wid ? KB : KF;
      unsigned h0 = h[4 * lane], h1 = h[4 * lane + 1];
      unsigned h2 = h[4 * lane + 2], h3 = h[4 * lane + 3];
      unsigned x = h0 + h1 + h2 + h3;
#pragma unroll
      for (int d = 1; d < 64; d <<= 1) {
        unsigned y = __shfl_down(x, d, 64);
        if (lane + d < 64) x += y;
      }
      unsigned long long m = __ballot(x >= K);
      int tl = 63 - __clzll(m);
      if (lane == tl) {
        unsigned s1 = x - h0, s2 = s1 - h1, s3 = s2 - h2, s4 = s3 - h3;
        int jj;
        unsigned A;
        if (s3 >= K) { jj = 3; A = s4; }
        else if (s2 >= K) { jj = 2; A = s3; }
        else if (s1 >= K) { jj = 1; A = s2; }
        else { jj = 0; A = s1; }
        selT[wid] = 4 * tl + jj;
        selA[wid] = A;
      }
    }
    __syncthreads();
    unsigned TF = selT[0], AF = selA[0];
    unsigned TB = selT[1], AB = selA[1];
    prefF = (prefF << 8) | TF; gtF += AF; KF -= AF;
    prefB = (prefB << 8) | TB; gtB += AB; KB -= AB;
    __syncthreads();
  }
  const unsigned tF = prefF, tB = prefB;
  const unsigned nGTF = gtF, needF = KF;
  const unsigned nGTB = gtB, needB = KB;
  if (tid == 0) { cntG[0] = 0; cntG[1] = 0; cntE[0] = 0; cntE[1] = 0; }
  __syncthreads();
#pragma unroll
  for (int j = 0; j < 9; ++j) {
    unsigned k = kF[j];
    if (k > tF) soutF[atomicAdd(&cntG[0], 1u)] = k;
    else if (k == tF) {
      unsigned e = atomicAdd(&cntE[0], 1u);
      if (e < needF) soutF[nGTF + e] = tF;
    }
    k = kB[j];
    if (k > tB) soutB[atomicAdd(&cntG[1], 1u)] = k;
    else if (k == tB) {
      unsigned e = atomicAdd(&cntE[1], 1u);
      if (e < needB) soutB[nGTB + e] = tB;
    }
  }
  __syncthreads();
  for (int kk = 2; kk <= 256; kk <<= 1) {
    for (int j = kk >> 1; j > 0; j >>= 1) {
      int t = tid, ixj = t ^ j;
      if (ixj > t) {
        bool up = ((t & kk) == 0);
        unsigned a = soutF[t], c = soutF[ixj];
        if (up ? (a > c) : (a < c)) { soutF[t] = c; soutF[ixj] = a; }
        a = soutB[t]; c = soutB[ixj];
        if (up ? (a > c) : (a < c)) { soutB[t] = c; soutB[ixj] = a; }
      }
      __syncthreads();
    }
  }
  size_t base = ((size_t)(b * 2304 + yx)) * 1312;
  xcat[base + 256 + tid] = f2bf(un_key(soutF[255 - tid]));
  xcat[base + 512 + tid] = f2bf(un_key(soutB[255 - tid]));
}

// ===== local top-k -> bf16 NHWC =====
__global__ __launch_bounds__(TPB) void topk_local_kernel(const float* __restrict__ klp,
                                                         const float* __restrict__ lm,
                                                         ushort_t* __restrict__ xcat) {
  __shared__ float sf[512];
  __shared__ float sb[512];
  const int tid = threadIdx.x;
  int bid = (blockIdx.x & 7) * 576 + (blockIdx.x >> 3);
  int b = bid / 2304, yx = bid - b * 2304;
  int y = yx / 48, x = yx - y * 48;
  for (int i = tid; i < 512; i += TPB) {
    float vf = -INFINITY, vb = -INFINITY;
    if (i < 289) {
      int dy = i / 17, dx = i - dy * 17;
      int sy = y + dy - 8, sx = x + dx - 8;
      float pv = 0.f;
      if (sy >= 0 && sy < 48 && sx >= 0 && sx < 48) pv = lm[(size_t)b * 2304 + sy * 48 + sx];
      float v = klp[((size_t)b * 289 + i) * 2304 + yx];
      vf = v * pv;
      vb = v * (1.0f - pv);
    }
    sf[i] = vf;
    sb[i] = vb;
  }
  for (int k = 2; k <= 512; k <<= 1) {
    for (int j = k >> 1; j > 0; j >>= 1) {
      __syncthreads();
      for (int t = tid; t < 512; t += TPB) {
        int ixj = t ^ j;
        if (ixj > t) {
          bool up = ((t & k) == 0);
          float a = sf[t], c = sf[ixj];
          if (up ? (a > c) : (a < c)) { sf[t] = c; sf[ixj] = a; }
          a = sb[t]; c = sb[ixj];
          if (up ? (a > c) : (a < c)) { sb[t] = c; sb[ixj] = a; }
        }
      }
    }
  }
  __syncthreads();
  size_t base = ((size_t)(b * 2304 + yx)) * 1312;
  xcat[base + 768 + tid] = f2bf(sf[511 - tid]);
  xcat[base + 1024 + tid] = f2bf(sb[511 - tid]);
}

// ===== NCHW fp32 -> NHWC fp32 transpose =====
__global__ __launch_bounds__(TPB) void tposef_kernel(const float* __restrict__ src,
                                                     float* __restrict__ dst, int C, int HW,
                                                     int DS) {
  __shared__ float tile[64][65];
  int px0 = blockIdx.x * 64;
  int c0 = blockIdx.y * 64;
  int b = blockIdx.z;
  int tid = threadIdx.x;
#pragma unroll
  for (int i = 0; i < 16; ++i) {
    int c = (tid >> 6) + i * 4, p = tid & 63;
    tile[c][p] = src[((size_t)b * C + c0 + c) * HW + px0 + p];
  }
  __syncthreads();
#pragma unroll
  for (int i = 0; i < 16; ++i) {
    int c = tid & 63, p = (tid >> 6) + i * 4;
    dst[((size_t)b * HW + px0 + p) * DS + c0 + c] = tile[c][p];
  }
}

// ===== NCHW fp32 -> NHWC bf16 transpose =====
__global__ __launch_bounds__(TPB) void tposeh_kernel(const float* __restrict__ src,
                                                     ushort_t* __restrict__ dst, int C, int HW,
                                                     int DS) {
  __shared__ float tile[64][65];
  int px0 = blockIdx.x * 64;
  int c0 = blockIdx.y * 64;
  int b = blockIdx.z;
  int tid = threadIdx.x;
#pragma unroll
  for (int i = 0; i < 16; ++i) {
    int c = (tid >> 6) + i * 4, p = tid & 63;
    tile[c][p] = src[((size_t)b * C + c0 + c) * HW + px0 + p];
  }
  __syncthreads();
#pragma unroll
  for (int i = 0; i < 16; ++i) {
    int c = tid & 63, p = (tid >> 6) + i * 4;
    dst[((size_t)b * HW + px0 + p) * DS + c0 + c] = f2bf(tile[c][p]);
  }
}

// ===== pm channel + zero pad channels of xcat (bf16) =====
__global__ __launch_bounds__(TPB) void pm_pad_kernel(const float* __restrict__ lm,
                                                     ushort_t* __restrict__ xcat) {
  int idx = blockIdx.x * TPB + threadIdx.x;
  if (idx >= 2 * 2304 * 32) return;
  int ch = idx & 31;
  int r = idx >> 5;
  xcat[(size_t)r * 1312 + 1280 + ch] = (ch == 0) ? f2bf(lm[r]) : (ushort_t)0;
}

// ===== weight preconvert: OIHW fp32 -> [chunk][kykx][cog][lane][8] split bf16 =====
__global__ __launch_bounds__(TPB) void wconv_kernel(const float* __restrict__ w,
                                                    ushort_t* __restrict__ whi,
                                                    ushort_t* __restrict__ wlo,
                                                    int CinW, int CIP, int CoutPad,
                                                    int CoutReal, int total) {
  int i = blockIdx.x * TPB + threadIdx.x;
  if (i >= total) return;
  int e = i & 7;
  int t = i >> 3;
  int l16 = t & 15; t >>= 4;
  int h4 = t & 3; t >>= 2;
  int NCOG = CoutPad >> 4;
  int cog = t % NCOG; t /= NCOG;
  int kykx = t % 9;
  int chunk = t / 9;
  int co = cog * 16 + l16;
  int ci = chunk * 32 + h4 * 8 + e;
  float v = 0.f;
  if (ci < CinW && co < CoutReal) v = w[((size_t)co * CinW + ci) * 9 + kykx];
  unsigned short h = f2bf(v);
  whi[i] = h;
  wlo[i] = f2bf(v - bf2f(h));
}

// ===== MFMA implicit-GEMM 3x3 conv, bf16 NHWC act, split-bf16 weights (2-term) =====
// tile: MB co x 128 px (16 rows x 8 cols); halo 18x10 bf16 staged per 32-ci chunk.
// LDS layout [ci-octet q4][180 px] of 16B items (conflict-free reads/writes).
template <int MFR, int ACT>
__global__ __launch_bounds__(TPB) void conv_mfma_kernel(
    const ushort_t* __restrict__ in, const ushort_t* __restrict__ whi,
    const ushort_t* __restrict__ wlo, const float* __restrict__ bias,
    ushort_t* __restrict__ outh, float* __restrict__ outf, float* __restrict__ partial,
    int CIP, int Cout, int H, int W, int S, int ci_per_s) {
  __shared__ uint4 sB[768];
  const int MB = MFR * 32;
  const int tid = threadIdx.x;
  const int lane = tid & 63;
  const int lo16 = lane & 15, hi4 = lane >> 4;
  const int wid = tid >> 6;
  const int wco = wid & 1, wpx = wid >> 1;
  const int tilesX = W >> 3;
  const int tx0 = (blockIdx.x % tilesX) << 3;
  const int ty0 = (blockIdx.x / tilesX) << 4;
  const int s = blockIdx.y % S;
  const int co0 = (blockIdx.y / S) * MB;
  const int b = blockIdx.z;
  const int NCOG = Cout >> 4;
  const size_t HW = (size_t)H * W;
  const ushort_t* inb = in + (size_t)b * HW * CIP;
  int ci_begin = s * ci_per_s;
  int ci_end = ci_begin + ci_per_s;
  if (ci_end > CIP) ci_end = CIP;
  f4 acc[MFR][4];
#pragma unroll
  for (int m = 0; m < MFR; ++m)
#pragma unroll
    for (int n = 0; n < 4; ++n) acc[m][n] = (f4){0.f, 0.f, 0.f, 0.f};

  for (int ci0 = ci_begin; ci0 < ci_end; ci0 += 32) {
    __syncthreads();
    // stage 180 px x 32 ci bf16 (720 x 16B items, layout [q4][pix])
#pragma unroll
    for (int it = 0; it < 3; ++it) {
      int u = it * TPB + tid;
      if (u < 720) {
        int q4 = u / 180;
        int pix = u - q4 * 180;
        int prow = pix / 10, pcol = pix - prow * 10;
        int gy = ty0 - 1 + prow, gx = tx0 - 1 + pcol;
        uint4 v = {0u, 0u, 0u, 0u};
        if (gy >= 0 && gy < H && gx >= 0 && gx < W)
          v = *(const uint4*)(inb + ((size_t)gy * W + gx) * CIP + ci0 + q4 * 8);
        sB[u] = v;
      }
    }
    __syncthreads();
    const int chunkIdx = ci0 >> 5;
#pragma unroll
    for (int ky = 0; ky < 3; ++ky) {
#pragma unroll
      for (int kx = 0; kx < 3; ++kx) {
        const int kykx = ky * 3 + kx;
        bh8 ah[MFR], al[MFR];
#pragma unroll
        for (int m = 0; m < MFR; ++m) {
          int cog = (co0 + wco * (MB / 2) + m * 16) >> 4;
          size_t woff = (((size_t)chunkIdx * 9 + kykx) * NCOG + cog) * 512 + (size_t)lane * 8;
          ah[m] = *(const bh8*)(whi + woff);
          al[m] = *(const bh8*)(wlo + woff);
        }
        bh8 bf[4];
#pragma unroll
        for (int n = 0; n < 4; ++n) {
          int pix = (wpx * 8 + n * 2 + (lo16 >> 3) + ky) * 10 + (lo16 & 7) + kx;
          union { uint4 q; bh8 v; } ub;
          ub.q = sB[hi4 * 180 + pix];
          bf[n] = ub.v;
        }
#pragma unroll
        for (int m = 0; m < MFR; ++m)
#pragma unroll
          for (int n = 0; n < 4; ++n) {
            acc[m][n] = __builtin_amdgcn_mfma_f32_16x16x32_bf16(ah[m], bf[n], acc[m][n], 0, 0, 0);
            acc[m][n] = __builtin_amdgcn_mfma_f32_16x16x32_bf16(al[m], bf[n], acc[m][n], 0, 0, 0);
          }
      }
    }
  }

#pragma unroll
  for (int m = 0; m < MFR; ++m) {
#pragma unroll
    for (int n = 0; n < 4; ++n) {
      int py = ty0 + wpx * 8 + n * 2 + (lo16 >> 3);
      int pxx = tx0 + (lo16 & 7);
      int co_r0 = co0 + wco * (MB / 2) + m * 16 + hi4 * 4;
      if (ACT == 1) {
        if (wco == 0 && m == 0 && hi4 == 0) {
          float v = acc[0][n][0] + bias[0];
          outf[(size_t)b * HW + (size_t)py * W + pxx] = 1.0f / (1.0f + expf(-v));
        }
      } else if (S == 1) {
        float4 bv = *(const float4*)(bias + co_r0);
        unsigned w0 = (unsigned)f2bf(acc[m][n][0] + bv.x) |
                      ((unsigned)f2bf(acc[m][n][1] + bv.y) << 16);
        unsigned w1 = (unsigned)f2bf(acc[m][n][2] + bv.z) |
                      ((unsigned)f2bf(acc[m][n][3] + bv.w) << 16);
        uint2 o = {w0, w1};
        *(uint2*)(outh + (((size_t)b * HW + (size_t)py * W + pxx) * Cout + co_r0)) = o;
      } else {
        float4 o = {acc[m][n][0], acc[m][n][1], acc[m][n][2], acc[m][n][3]};
        *(float4*)(partial + (((size_t)(s * 2 + b) * HW + (size_t)py * W + pxx) * Cout + co_r0)) = o;
      }
    }
  }
}

// ===== split-K reduce + bias -> bf16 NHWC =====
__global__ __launch_bounds__(TPB) void reduce_nhwc_kernel(const float* __restrict__ partial,
                                                          const float* __restrict__ bias,
                                                          ushort_t* __restrict__ outh, int S,
                                                          int Cout, int HW, int total4) {
  int i = blockIdx.x * TPB + threadIdx.x;
  if (i >= total4) return;
  int e = i * 4;
  int CHW = Cout * HW;
  int b = e / CHW;
  int rem = e - b * CHW;
  int co = e % Cout;
  float4 acc = {0.f, 0.f, 0.f, 0.f};
  for (int ss = 0; ss < S; ++ss) {
    const float4 t = *(const float4*)(partial + (size_t)(ss * 2 + b) * CHW + rem);
    acc.x += t.x; acc.y += t.y; acc.z += t.z; acc.w += t.w;
  }
  float4 bv = *(const float4*)(bias + co);
  unsigned w0 = (unsigned)f2bf(acc.x + bv.x) | ((unsigned)f2bf(acc.y + bv.y) << 16);
  unsigned w1 = (unsigned)f2bf(acc.z + bv.z) | ((unsigned)f2bf(acc.w + bv.w) << 16);
  uint2 o = {w0, w1};
  *(uint2*)(outh + (size_t)b * CHW + rem) = o;
}

// ===== InstanceNorm on bf16 NHWC: stats -> finalize -> apply in place =====
__global__ __launch_bounds__(TPB) void in_stats_kernel(const ushort_t* __restrict__ x,
                                                       float* __restrict__ stat, int N, int C) {
  __shared__ float ls[4][64], lq[4][64];
  int CG = C >> 6;
  int b = blockIdx.x / CG, cg = blockIdx.x % CG;
  int slice = blockIdx.y;
  int c = threadIdx.x & 63, p = threadIdx.x >> 6;
  int cnt = N >> 6;
  int base = slice * cnt;
  float s = 0.f, q = 0.f;
  const ushort_t* xp = x + ((size_t)b * N) * C + cg * 64 + c;
  for (int px = base + p; px < base + cnt; px += 4) {
    float v = bf2f(xp[(size_t)px * C]);
    s += v;
    q = fmaf(v, v, q);
  }
  ls[p][c] = s;
  lq[p][c] = q;
  __syncthreads();
  if (threadIdx.x < 64) {
    float S = ls[0][threadIdx.x] + ls[1][threadIdx.x] + ls[2][threadIdx.x] + ls[3][threadIdx.x];
    float Q = lq[0][threadIdx.x] + lq[1][threadIdx.x] + lq[2][threadIdx.x] + lq[3][threadIdx.x];
    int Ctot = 2 * C;
    int idx = b * C + cg * 64 + threadIdx.x;
    stat[(size_t)(slice * Ctot + idx) * 2] = S;
    stat[(size_t)(slice * Ctot + idx) * 2 + 1] = Q;
  }
}

__global__ __launch_bounds__(TPB) void in_final_kernel(const float* __restrict__ stat,
                                                       float* __restrict__ mean,
                                                       float* __restrict__ inv, int N, int Ctot) {
  int idx = blockIdx.x * TPB + threadIdx.x;
  if (idx >= Ctot) return;
  float S = 0.f, Q = 0.f;
  for (int sl = 0; sl < 64; ++sl) {
    S += stat[(size_t)(sl * Ctot + idx) * 2];
    Q += stat[(size_t)(sl * Ctot + idx) * 2 + 1];
  }
  float m = S / (float)N;
  float var = Q / (float)N - m * m;
  if (var < 0.f) var = 0.f;
  mean[idx] = m;
  inv[idx] = 1.0f / sqrtf(var + 1e-5f);
}

// RES: 0 none, 1 bf16 residual, 2 fp32 residual; in-place on bf16 buffer
template <int RES>
__global__ __launch_bounds__(TPB) void in_apply_kernel(ushort_t* __restrict__ x,
                                                       const float* __restrict__ mean,
                                                       const float* __restrict__ inv,
                                                       const void* __restrict__ res, int N,
                                                       int C, int total4) {
  int NC = N * C;
  for (int i = blockIdx.x * TPB + threadIdx.x; i < total4; i += gridDim.x * TPB) {
    int e = i * 4;
    int c = e % C;
    int b = e / NC;
    int midx = b * C + c;
    float4 m4 = *(const float4*)(mean + midx);
    float4 i4 = *(const float4*)(inv + midx);
    uint2 v2 = *(uint2*)(x + e);
    float o0 = fmaxf((bf2f((ushort_t)(v2.x & 0xffff)) - m4.x) * i4.x, 0.f);
    float o1 = fmaxf((bf2f((ushort_t)(v2.x >> 16)) - m4.y) * i4.y, 0.f);
    float o2 = fmaxf((bf2f((ushort_t)(v2.y & 0xffff)) - m4.z) * i4.z, 0.f);
    float o3 = fmaxf((bf2f((ushort_t)(v2.y >> 16)) - m4.w) * i4.w, 0.f);
    if (RES == 1) {
      uint2 r2 = *(const uint2*)((const ushort_t*)res + e);
      o0 += bf2f((ushort_t)(r2.x & 0xffff));
      o1 += bf2f((ushort_t)(r2.x >> 16));
      o2 += bf2f((ushort_t)(r2.y & 0xffff));
      o3 += bf2f((ushort_t)(r2.y >> 16));
    } else if (RES == 2) {
      const float4 r = *(const float4*)((const float*)res + e);
      o0 += r.x; o1 += r.y; o2 += r.z; o3 += r.w;
    }
    uint2 o;
    o.x = (unsigned)f2bf(o0) | ((unsigned)f2bf(o1) << 16);
    o.y = (unsigned)f2bf(o2) | ((unsigned)f2bf(o3) << 16);
    *(uint2*)(x + e) = o;
  }
}

// ===== bilinear resize align_corners, bf16 NHWC =====
__global__ __launch_bounds__(TPB) void resize4_kernel(const ushort_t* __restrict__ in,
                                                      ushort_t* __restrict__ out, int C,
                                                      int hin, int win, int Hout, int Wout,
                                                      float r, int total4) {
  for (int i = blockIdx.x * TPB + threadIdx.x; i < total4; i += gridDim.x * TPB) {
    int e = i * 4;
    int c = e % C;
    int t = e / C;
    int X = t % Wout;
    int t2 = t / Wout;
    int Y = t2 % Hout;
    int b = t2 / Hout;
    float ys = Y * r, xs = X * r;
    int y0 = (int)floorf(ys);
    if (y0 > hin - 1) y0 = hin - 1;
    int x0 = (int)floorf(xs);
    if (x0 > win - 1) x0 = win - 1;
    int y1 = y0 + 1 < hin ? y0 + 1 : hin - 1;
    int x1 = x0 + 1 < win ? x0 + 1 : win - 1;
    float wy = ys - (float)y0, wx = xs - (float)x0;
    const ushort_t* ip = in + ((size_t)b * hin * win) * C + c;
    uint2 a2 = *(const uint2*)(ip + ((size_t)y0 * win + x0) * C);
    uint2 b2 = *(const uint2*)(ip + ((size_t)y0 * win + x1) * C);
    uint2 c2 = *(const uint2*)(ip + ((size_t)y1 * win + x0) * C);
    uint2 d2 = *(const uint2*)(ip + ((size_t)y1 * win + x1) * C);
    uint2 o;
    float w00 = (1.f - wy) * (1.f - wx), w01 = (1.f - wy) * wx;
    float w10 = wy * (1.f - wx), w11 = wy * wx;
    float v0 = bf2f((ushort_t)(a2.x & 0xffff)) * w00 + bf2f((ushort_t)(b2.x & 0xffff)) * w01 +
               bf2f((ushort_t)(c2.x & 0xffff)) * w10 + bf2f((ushort_t)(d2.x & 0xffff)) * w11;
    float v1 = bf2f((ushort_t)(a2.x >> 16)) * w00 + bf2f((ushort_t)(b2.x >> 16)) * w01 +
               bf2f((ushort_t)(c2.x >> 16)) * w10 + bf2f((ushort_t)(d2.x >> 16)) * w11;
    float v2 = bf2f((ushort_t)(a2.y & 0xffff)) * w00 + bf2f((ushort_t)(b2.y & 0xffff)) * w01 +
               bf2f((ushort_t)(c2.y & 0xffff)) * w10 + bf2f((ushort_t)(d2.y & 0xffff)) * w11;
    float v3 = bf2f((ushort_t)(a2.y >> 16)) * w00 + bf2f((ushort_t)(b2.y >> 16)) * w01 +
               bf2f((ushort_t)(c2.y >> 16)) * w10 + bf2f((ushort_t)(d2.y >> 16)) * w11;
    o.x = (unsigned)f2bf(v0) | ((unsigned)f2bf(v1) << 16);
    o.y = (unsigned)f2bf(v2) | ((unsigned)f2bf(v3) << 16);
    *(uint2*)(out + e) = o;
  }
}

extern "C" void kernel_launch(void* const* d_in, const int* in_sizes, int n_in,
                              void* d_out, int out_size, void* d_ws, size_t ws_size,
                              hipStream_t stream) {
  (void)in_sizes; (void)n_in; (void)out_size;
  const float* p3 = (const float*)d_in[0];
  const float* p2 = (const float*)d_in[1];
  const float* p1 = (const float*)d_in[2];
  const float* kg1 = (const float*)d_in[3];
  const float* klp = (const float*)d_in[4];
  const float* key_mask = (const float*)d_in[5];
  const float* pre_mask = (const float*)d_in[6];
  const float* conv_top_w = (const float*)d_in[7];
  const float* conv_top_b = (const float*)d_in[8];
  const float* aic_top_w1 = (const float*)d_in[9];
  const float* aic_top_b1 = (const float*)d_in[10];
  const float* aic_top_w2 = (const float*)d_in[11];
  const float* aic_top_b2 = (const float*)d_in[12];
  const float* r1a_w1 = (const float*)d_in[13];
  const float* r1a_b1 = (const float*)d_in[14];
  const float* r1a_w2 = (const float*)d_in[15];
  const float* r1a_b2 = (const float*)d_in[16];
  const float* r1b_w1 = (const float*)d_in[17];
  const float* r1b_b1 = (const float*)d_in[18];
  const float* r1b_w2 = (const float*)d_in[19];
  const float* r1b_b2 = (const float*)d_in[20];
  const float* r2a_w1 = (const float*)d_in[21];
  const float* r2a_b1 = (const float*)d_in[22];
  const float* r2a_w2 = (const float*)d_in[23];
  const float* r2a_b2 = (const float*)d_in[24];
  const float* r2b_w1 = (const float*)d_in[25];
  const float* r2b_b1 = (const float*)d_in[26];
  const float* r2b_w2 = (const float*)d_in[27];
  const float* r2b_b2 = (const float*)d_in[28];
  const float* dec_w = (const float*)d_in[29];
  const float* dec_b = (const float*)d_in[30];
  const float* pred_w = (const float*)d_in[31];
  const float* pred_b = (const float*)d_in[32];
  float* outp = (float*)d_out;

  // workspace layout (float units)
  const size_t OFF_GM = 0;            // 4608
  const size_t OFF_LM = 4608;         // 4608
  const size_t OFF_STAT = 9216;       // 65536
  const size_t OFF_MEAN = 74752;      // 512
  const size_t OFF_INV = 75264;       // 512
  const size_t OFF_WB = 75776;        // 3,022,848 f (2x 3,022,848 ushorts)
  const size_t OFF_AH0 = 3098624;     // 3,022,848 f  xcat_h / y96_h / z1_h
  const size_t OFF_AH1 = 6121472;     // 589,824 f    a0_h / h96_h / d96_h
  const size_t OFF_AH2 = 6711296;     // 147,456 f    h48_h
  const size_t OFF_AH3 = 6858752;     // 589,824 f    a1_h
  const size_t OFF_AH4 = 7448576;     // 2,359,296 f  R1_h / zA_h
  const size_t OFF_AH5 = 9807872;     // 2,359,296 f  R0_h / zB_h
  const size_t OFF_P1T = 12167168;    // 4,718,592 f  partials (<=4.72M) / p1t
  const size_t OFF_P2T = 16885760;    // 1,179,648 f  p2t (bf16)
  const size_t TOTAL_F = 18065408;    // ~72.3 MB
  if (ws_size < TOTAL_F * sizeof(float)) return;

  float* ws = (float*)d_ws;
  float* gm = ws + OFF_GM;
  float* lm = ws + OFF_LM;
  float* statb = ws + OFF_STAT;
  float* meanb = ws + OFF_MEAN;
  float* invb = ws + OFF_INV;
  ushort_t* wbh = (ushort_t*)(ws + OFF_WB);
  ushort_t* wbl = wbh + 3022848;
  ushort_t* xcat_h = (ushort_t*)(ws + OFF_AH0);
  ushort_t* y96_h = (ushort_t*)(ws + OFF_AH0);
  ushort_t* z1_h = (ushort_t*)(ws + OFF_AH0);
  ushort_t* a0_h = (ushort_t*)(ws + OFF_AH1);
  ushort_t* h96_h = (ushort_t*)(ws + OFF_AH1);
  ushort_t* d96_h = (ushort_t*)(ws + OFF_AH1);
  ushort_t* h48_h = (ushort_t*)(ws + OFF_AH2);
  ushort_t* a1_h = (ushort_t*)(ws + OFF_AH3);
  ushort_t* R1_h = (ushort_t*)(ws + OFF_AH4);
  ushort_t* zA_h = (ushort_t*)(ws + OFF_AH4);
  ushort_t* R0_h = (ushort_t*)(ws + OFF_AH5);
  ushort_t* zB_h = (ushort_t*)(ws + OFF_AH5);
  float* Pbuf = ws + OFF_P1T;          // small partials
  float* PbufTop = ws + OFF_AH4;       // conv_top S=7 partial: 33M B fits AH4+AH5+P1T
  float* p1t = ws + OFF_P1T;
  ushort_t* p2t = (ushort_t*)(ws + OFF_P2T);

  // pooled masks + xcat assembly
  pool8_kernel<<<(2 * 2304 + TPB - 1) / TPB, TPB, 0, stream>>>(key_mask, gm, 2 * 2304);
  pool8_kernel<<<(2 * 2304 + TPB - 1) / TPB, TPB, 0, stream>>>(pre_mask, lm, 2 * 2304);
  topk_global_kernel<<<2 * 2304, TPB, 0, stream>>>(kg1, gm, xcat_h);
  topk_local_kernel<<<2 * 2304, TPB, 0, stream>>>(klp, lm, xcat_h);
  tposeh_kernel<<<dim3(36, 4, 2), TPB, 0, stream>>>(p3, xcat_h, 256, 2304, 1312);
  pm_pad_kernel<<<(2 * 2304 * 32 + TPB - 1) / TPB, TPB, 0, stream>>>(lm, xcat_h);

  auto conv = [&](const ushort_t* src, const float* w, const float* bb, ushort_t* dsth,
                  float* dstf, float* part, int CinW, int CIP, int CoutPad, int CoutReal,
                  int H, int W, int S, int MB, int act) {
    int wtotal = CoutPad * 9 * CIP;
    wconv_kernel<<<(wtotal + TPB - 1) / TPB, TPB, 0, stream>>>(w, wbh, wbl, CinW, CIP,
                                                               CoutPad, CoutReal, wtotal);
    int chunks = CIP / 32;
    int cps = ((chunks + S - 1) / S) * 32;
    dim3 grid((W / 8) * (H / 16), (CoutPad / MB) * S, 2);
    if (MB == 128)
      conv_mfma_kernel<4, 0><<<grid, TPB, 0, stream>>>(src, wbh, wbl, bb, dsth, dstf, part,
                                                       CIP, CoutPad, H, W, S, cps);
    else if (act == 1)
      conv_mfma_kernel<2, 1><<<grid, TPB, 0, stream>>>(src, wbh, wbl, bb, dsth, dstf, part,
                                                       CIP, CoutPad, H, W, S, cps);
    else
      conv_mfma_kernel<2, 0><<<grid, TPB, 0, stream>>>(src, wbh, wbl, bb, dsth, dstf, part,
                                                       CIP, CoutPad, H, W, S, cps);
    if (S > 1) {
      int HW = H * W;
      int total4 = 2 * CoutPad * HW / 4;
      reduce_nhwc_kernel<<<(total4 + TPB - 1) / TPB, TPB, 0, stream>>>(part, bb, dsth, S,
                                                                       CoutPad, HW, total4);
    }
  };
  auto inorm = [&](ushort_t* x, int C, int N, int resMode, const void* res) {
    dim3 g1(2 * (C / 64), 64);
    in_stats_kernel<<<g1, TPB, 0, stream>>>(x, statb, N, C);
    int Ctot = 2 * C;
    in_final_kernel<<<(Ctot + TPB - 1) / TPB, TPB, 0, stream>>>(statb, meanb, invb, N, Ctot);
    int total4 = 2 * N * C / 4;
    int g = (total4 + TPB - 1) / TPB;
    if (g > 4096) g = 4096;
    if (resMode == 1)
      in_apply_kernel<1><<<g, TPB, 0, stream>>>(x, meanb, invb, res, N, C, total4);
    else if (resMode == 2)
      in_apply_kernel<2><<<g, TPB, 0, stream>>>(x, meanb, invb, res, N, C, total4);
    else
      in_apply_kernel<0><<<g, TPB, 0, stream>>>(x, meanb, invb, res, N, C, total4);
  };

  // ---- top fuse @48 ----
  conv(xcat_h, conv_top_w, conv_top_b, a0_h, nullptr, PbufTop, 1281, 1312, 256, 256, 48, 48, 7, 128, 0);
  conv(a0_h, aic_top_w1, aic_top_b1, h48_h, nullptr, Pbuf, 256, 256, 64, 64, 48, 48, 8, 64, 0);
  inorm(h48_h, 64, 2304, 0, nullptr);
  conv(h48_h, aic_top_w2, aic_top_b2, a1_h, nullptr, Pbuf, 64, 64, 256, 256, 48, 48, 2, 64, 0);
  inorm(a1_h, 256, 2304, 0, nullptr);

  // ---- 48 -> 96 ----
  {
    int total4 = 2 * 96 * 96 * 256 / 4;
    int g = (total4 + TPB - 1) / TPB; if (g > 4096) g = 4096;
    resize4_kernel<<<g, TPB, 0, stream>>>(a1_h, y96_h, 256, 48, 48, 96, 96, 47.f / 95.f, total4);
  }
  conv(y96_h, r1a_w1, r1a_b1, h96_h, nullptr, Pbuf, 256, 256, 64, 64, 96, 96, 4, 64, 0);
  tposeh_kernel<<<dim3(144, 4, 2), TPB, 0, stream>>>(p2, p2t, 256, 9216, 256);
  inorm(h96_h, 64, 9216, 0, nullptr);
  conv(h96_h, r1a_w2, r1a_b2, R1_h, nullptr, nullptr, 64, 64, 256, 256, 96, 96, 1, 64, 0);
  inorm(R1_h, 256, 9216, 1, p2t);
  conv(R1_h, r1b_w1, r1b_b1, h96_h, nullptr, Pbuf, 256, 256, 64, 64, 96, 96, 4, 64, 0);
  inorm(h96_h, 64, 9216, 0, nullptr);
  conv(h96_h, r1b_w2, r1b_b2, R0_h, nullptr, nullptr, 64, 64, 256, 256, 96, 96, 1, 64, 0);
  inorm(R0_h, 256, 9216, 0, nullptr);
  conv(R0_h, dec_w, dec_b, d96_h, nullptr, Pbuf, 256, 256, 64, 64, 96, 96, 4, 64, 0);
  // p1 -> NHWC fp32 (partials consumed by dec's reduce)
  tposef_kernel<<<dim3(576, 1, 2), TPB, 0, stream>>>(p1, p1t, 64, 36864, 64);

  // ---- 96 -> 192 ----
  {
    int total4 = 2 * 192 * 192 * 64 / 4;
    int g = (total4 + TPB - 1) / TPB; if (g > 4096) g = 4096;
    resize4_kernel<<<g, TPB, 0, stream>>>(d96_h, z1_h, 64, 96, 96, 192, 192, 95.f / 191.f, total4);
  }
  conv(z1_h, r2a_w1, r2a_b1, zA_h, nullptr, nullptr, 64, 64, 64, 64, 192, 192, 1, 64, 0);
  inorm(zA_h, 64, 36864, 0, nullptr);
  conv(zA_h, r2a_w2, r2a_b2, zB_h, nullptr, nullptr, 64, 64, 64, 64, 192, 192, 1, 64, 0);
  inorm(zB_h, 64, 36864, 2, p1t);
  conv(zB_h, r2b_w1, r2b_b1, zA_h, nullptr, nullptr, 64, 64, 64, 64, 192, 192, 1, 64, 0);
  inorm(zA_h, 64, 36864, 0, nullptr);
  conv(zA_h, r2b_w2, r2b_b2, zB_h, nullptr, nullptr, 64, 64, 64, 64, 192, 192, 1, 64, 0);
  inorm(zB_h, 64, 36864, 0, nullptr);

  // ---- pred head: 64 -> 1 + sigmoid -> d_out (NCHW [2,1,192,192]) ----
  conv(zB_h, pred_w, pred_b, nullptr, outp, nullptr, 64, 64, 64, 1, 192, 192, 1, 64, 1);
}